// Round 13
// baseline (461.795 us; speedup 1.0000x reference)
//
#include <hip/hip_runtime.h>
#include <hip/hip_bf16.h>
#include <hip/hip_fp16.h>

#define NN 100000
#define NE 3200000
#define FIN 256
#define F1 16
#define F2 32
#define CO 64
#define NC 1000
#define NBLK 391   /* ceil(NN/256) */
#define GBLK 1563  /* ceil(NN/64) gemm1 grid (64-thread blocks, 1 row/thread) */
#define NPART 8
#define NGRP 32    /* counter split per bin */
#define PSZ 12500  /* NN / NPART */
#define BK 5       /* edges per thread in pcount/bucket; 2500 blocks * 256 * 5 = NE */
#define CH 16      /* chunks per partition for hist/place */

// workspace layout (float offsets) — total 11,502,080 floats = 46.0 MB
#define OFF_DINV 0
#define OFF_CUR  100352
#define OFF_DEG  200704
#define OFF_ECOL 301056
#define OFF_MISC 3501056   /* pc[256], pcur[256]@256, pbase[8]@512, pcnt8[8]@520,
                              pool[64]@528, bsum[391]@592 — ends 983 < 1024 */
#define OFF_DPART 3502080
#define OFF_SPART 6702080
#define OFF_HIST 9902080   /* u32[NPART*CH*PSZ] = 1.6M */
#define OFF_H1S  3502080   /* fp16, 800K floats; overlays dpart (dead after place) */
#define OFF_H2S  6702080   /* fp16, 1.6M floats (ends 8302080); overlays spart (dead after place) */
#define OFF_OUT2 3502080   /* f32 3.2M floats: 3502080..6702080 — overlays h1h+dpart (dead
                              after gathm), ends exactly at h2h start. MUST NOT cross 6702080. */

__device__ __forceinline__ unsigned enc_f(float f) {
    unsigned u = __float_as_uint(f);
    return (u & 0x80000000u) ? ~u : (u | 0x80000000u);
}
__device__ __forceinline__ float dec_f(unsigned u) {
    return (u & 0x80000000u) ? __uint_as_float(u & 0x7fffffffu) : __uint_as_float(~u);
}

// ---------- K0a: partition edge counts into pc[bin*NGRP + block%NGRP] ----------
__global__ __launch_bounds__(256) void k_pcount(const int* __restrict__ ei,
                                                unsigned* __restrict__ pc) {
    int t = threadIdx.x, lane = t & 63;
    int g = blockIdx.x & (NGRP - 1);
    int base = blockIdx.x * (256 * BK) + t;
    unsigned cnt = 0;
    #pragma unroll
    for (int k = 0; k < BK; ++k) {
        int bin = (unsigned)ei[NE + base + k * 256] / PSZ;
        #pragma unroll
        for (int b = 0; b < 8; ++b) {
            unsigned long long m = __ballot(bin == b);
            if (lane == b) cnt += (unsigned)__popcll(m);
        }
    }
    if (lane < 8) atomicAdd(&pc[lane * NGRP + g], cnt);
}

// ---------- K0b: scan 256 split counters (bin-major) -> pcur, pbase, pcnt8 ----------
__global__ __launch_bounds__(256) void k_pscan(const unsigned* __restrict__ pc,
                                               unsigned* __restrict__ pcur,
                                               unsigned* __restrict__ pbase,
                                               unsigned* __restrict__ pcnt8) {
    __shared__ unsigned S[256];
    int t = threadIdx.x;
    unsigned v = pc[t];
    S[t] = v;
    __syncthreads();
    for (int off = 1; off < 256; off <<= 1) {
        unsigned u = (t >= off) ? S[t - off] : 0u;
        __syncthreads();
        S[t] += u;
        __syncthreads();
    }
    pcur[t] = S[t] - v;                       // exclusive prefix
    if ((t & 31) == 0) pbase[t >> 5] = S[t] - v;
    if ((t & 31) == 31) {
        unsigned start = S[t & ~31] - pc[t & ~31];
        pcnt8[t >> 5] = S[t] - start;
    }
}

// ---------- K0c: bucket edges into partition-segmented (dst,src) arrays ----------
__global__ __launch_bounds__(256) void k_bucket(const int* __restrict__ ei,
                                                unsigned* __restrict__ pcur,
                                                int* __restrict__ dpart,
                                                int* __restrict__ spart) {
    int t = threadIdx.x, lane = t & 63;
    int g = blockIdx.x & (NGRP - 1);
    int base = blockIdx.x * (256 * BK) + t;
    int dst[BK], src[BK];
    #pragma unroll
    for (int k = 0; k < BK; ++k) {
        dst[k] = ei[NE + base + k * 256];
        src[k] = ei[base + k * 256];
    }
    unsigned long long lt = (lane == 63) ? 0x7fffffffffffffffull
                                         : ((1ull << lane) - 1ull);
    unsigned cnt = 0;
    #pragma unroll
    for (int k = 0; k < BK; ++k) {
        int bin = (unsigned)dst[k] / PSZ;
        #pragma unroll
        for (int b = 0; b < 8; ++b) {
            unsigned long long m = __ballot(bin == b);
            if (lane == b) cnt += (unsigned)__popcll(m);
        }
    }
    unsigned run = 0;
    if (lane < 8) run = atomicAdd(&pcur[lane * NGRP + g], cnt);
    #pragma unroll
    for (int k = 0; k < BK; ++k) {
        int bin = (unsigned)dst[k] / PSZ;
        unsigned long long mym = 0;
        unsigned myrun = 0;
        #pragma unroll
        for (int b = 0; b < 8; ++b) {
            unsigned long long m = __ballot(bin == b);
            unsigned r = __shfl(run, b);
            if (bin == b) { mym = m; myrun = r; }
            if (lane == b) run += (unsigned)__popcll(m);
        }
        unsigned pos = myrun + (unsigned)__popcll(mym & lt);
        dpart[pos] = dst[k];
        spart[pos] = src[k];
    }
}

// ---------- K0d: per-chunk LDS histograms -> hist[p][c][i] ----------
__global__ __launch_bounds__(256) void k_hist(const unsigned* __restrict__ pbase,
                                              const unsigned* __restrict__ pcnt,
                                              const int* __restrict__ dpart,
                                              unsigned* __restrict__ hist) {
    __shared__ unsigned lh[PSZ];
    int p = blockIdx.x & 7;
    int c = blockIdx.x >> 3;               // 0..CH-1
    int t = threadIdx.x;
    for (int i = t; i < PSZ; i += 256) lh[i] = 0;
    __syncthreads();
    unsigned s = pbase[p], n = pcnt[p];
    unsigned c0 = s + (unsigned)(((unsigned long long)n * c) / CH);
    unsigned c1 = s + (unsigned)(((unsigned long long)n * (c + 1)) / CH);
    int pb = p * PSZ;
    for (unsigned j = c0 + t; j < c1; j += 256)
        atomicAdd(&lh[dpart[j] - pb], 1u);
    __syncthreads();
    unsigned* hrow = hist + (unsigned)(p * CH + c) * PSZ;
    for (int i = t; i < PSZ; i += 256) hrow[i] = lh[i];
}

// ---------- K0e: scan chunk counts per bin -> chunk bases (in place) + deg ----------
__global__ __launch_bounds__(256) void k_colscan(unsigned* __restrict__ hist,
                                                 unsigned* __restrict__ deg) {
    int gid = blockIdx.x * 256 + threadIdx.x;
    if (gid >= NN) return;
    int p = gid / PSZ, i = gid % PSZ;
    unsigned run = 0;
    #pragma unroll
    for (int c = 0; c < CH; ++c) {
        unsigned idx = (unsigned)(p * CH + c) * PSZ + i;
        unsigned v = hist[idx];
        hist[idx] = run;
        run += v;
    }
    deg[gid] = run;
}

// ---------- K1a: per-block degree sums ----------
__global__ void k_bsum(const unsigned* __restrict__ deg, unsigned* __restrict__ bsum) {
    __shared__ unsigned W[4];
    int t = threadIdx.x;
    int i = blockIdx.x * 256 + t;
    unsigned d = (i < NN) ? deg[i] : 0u;
    #pragma unroll
    for (int off = 1; off < 64; off <<= 1) d += __shfl_xor(d, off);
    if ((t & 63) == 0) W[t >> 6] = d;
    __syncthreads();
    if (t == 0) bsum[blockIdx.x] = W[0] + W[1] + W[2] + W[3];
}

// ---------- K1b: exclusive scan of block sums (1 block) ----------
__global__ __launch_bounds__(512) void k_bscan(unsigned* __restrict__ bsum) {
    __shared__ unsigned S[512];
    int t = threadIdx.x;
    unsigned v = (t < NBLK) ? bsum[t] : 0u;
    S[t] = v;
    __syncthreads();
    for (int off = 1; off < 512; off <<= 1) {
        unsigned u = (t >= off) ? S[t - off] : 0u;
        __syncthreads();
        S[t] += u;
        __syncthreads();
    }
    if (t < NBLK) bsum[t] = S[t] - v;   // exclusive prefix
}

// ---------- K1c: per-block scan -> cursor[i] = rowptr[i+1] (inclusive), dinv ----------
__global__ void k_cscan(const unsigned* __restrict__ deg, const unsigned* __restrict__ bsum,
                        unsigned* __restrict__ cursor, float* __restrict__ dinv) {
    __shared__ unsigned S[256];
    int t = threadIdx.x;
    int i = blockIdx.x * 256 + t;
    unsigned d = (i < NN) ? deg[i] : 0u;
    S[t] = d;
    __syncthreads();
    for (int off = 1; off < 256; off <<= 1) {
        unsigned u = (t >= off) ? S[t - off] : 0u;
        __syncthreads();
        S[t] += u;
        __syncthreads();
    }
    if (i < NN) {
        cursor[i] = bsum[blockIdx.x] + S[t];       // inclusive = rowptr[i+1]
        dinv[i] = rsqrtf((float)(d + 1u));
    }
}

// ---------- K2: place edges via LDS cursors (no global atomics) ----------
__global__ __launch_bounds__(256) void k_place(const unsigned* __restrict__ pbase,
                                               const unsigned* __restrict__ pcnt,
                                               const int* __restrict__ dpart,
                                               const int* __restrict__ spart,
                                               const unsigned* __restrict__ hist,
                                               const unsigned* __restrict__ cursor,
                                               int* __restrict__ ecol) {
    __shared__ unsigned lcur[PSZ];
    int p = blockIdx.x & 7;
    int c = blockIdx.x >> 3;
    int t = threadIdx.x;
    int pb = p * PSZ;
    const unsigned* hrow = hist + (unsigned)(p * CH + c) * PSZ;
    for (int i = t; i < PSZ; i += 256) {
        int gi = pb + i;
        unsigned rowstart = gi ? cursor[gi - 1] : 0u;
        lcur[i] = rowstart + hrow[i];
    }
    __syncthreads();
    unsigned s = pbase[p], n = pcnt[p];
    unsigned c0 = s + (unsigned)(((unsigned long long)n * c) / CH);
    unsigned c1 = s + (unsigned)(((unsigned long long)n * (c + 1)) / CH);
    for (unsigned j = c0 + t; j < c1; j += 256) {
        int dst = dpart[j];
        int src = spart[j];
        unsigned pos = atomicAdd(&lcur[dst - pb], 1u);
        ecol[pos] = src;
    }
}

// ---------- K3: h1h = fp16((X @ W1) * dinv[row]) — thread-per-row, no barriers ----------
__device__ __forceinline__ void fma16(float xk, const float4* __restrict__ w4,
                                      float* __restrict__ acc) {
    float4 a = w4[0], b = w4[1], c = w4[2], d = w4[3];
    acc[0]  += xk * a.x; acc[1]  += xk * a.y; acc[2]  += xk * a.z; acc[3]  += xk * a.w;
    acc[4]  += xk * b.x; acc[5]  += xk * b.y; acc[6]  += xk * b.z; acc[7]  += xk * b.w;
    acc[8]  += xk * c.x; acc[9]  += xk * c.y; acc[10] += xk * c.z; acc[11] += xk * c.w;
    acc[12] += xk * d.x; acc[13] += xk * d.y; acc[14] += xk * d.z; acc[15] += xk * d.w;
}

__global__ __launch_bounds__(64) void k_gemm1(const float* __restrict__ X,
                                              const float* __restrict__ W1,
                                              const float* __restrict__ dinv,
                                              __half2* __restrict__ h1h) {
    __shared__ float Ws[4096];   // W1 [256][16]
    int t = threadIdx.x;
    {
        float4* Ws4 = (float4*)Ws;
        const float4* W14 = (const float4*)W1;
        #pragma unroll
        for (int i = 0; i < 16; ++i) Ws4[t + i * 64] = W14[t + i * 64];
    }
    __syncthreads();
    int row = blockIdx.x * 64 + t;
    if (row >= NN) return;

    const float4* xr = (const float4*)(X + (size_t)row * FIN);
    float acc[16] = {};
    float4 A0 = xr[0], A1 = xr[1], A2 = xr[2], A3 = xr[3];

#define DO4(xq, kb) \
    fma16((xq).x, (const float4*)&Ws[(kb) * 16],        acc); \
    fma16((xq).y, (const float4*)&Ws[((kb) + 1) * 16],  acc); \
    fma16((xq).z, (const float4*)&Ws[((kb) + 2) * 16],  acc); \
    fma16((xq).w, (const float4*)&Ws[((kb) + 3) * 16],  acc);

    #pragma unroll 1
    for (int c = 0; c < 8; ++c) {
        int kb = c * 32;
        float4 B0 = xr[c * 8 + 4], B1 = xr[c * 8 + 5],
               B2 = xr[c * 8 + 6], B3 = xr[c * 8 + 7];
        DO4(A0, kb);      DO4(A1, kb + 4);
        DO4(A2, kb + 8);  DO4(A3, kb + 12);
        if (c < 7) {
            A0 = xr[c * 8 + 8];  A1 = xr[c * 8 + 9];
            A2 = xr[c * 8 + 10]; A3 = xr[c * 8 + 11];
        }
        DO4(B0, kb + 16); DO4(B1, kb + 20);
        DO4(B2, kb + 24); DO4(B3, kb + 28);
    }
#undef DO4

    float dv = dinv[row];
    union { __half2 h[8]; uint4 u[2]; } pk;
    #pragma unroll
    for (int o = 0; o < 8; ++o)
        pk.h[o] = __floats2half2_rn(acc[2 * o] * dv, acc[2 * o + 1] * dv);
    uint4* dst = (uint4*)(h1h + (size_t)row * 8);
    dst[0] = pk.u[0];
    dst[1] = pk.u[1];
}

// ---------- K4: fused gather-1 + gemm2 — node per 8-lane group (8 nodes/wave) ----------
__global__ __launch_bounds__(256) void k_gathm(const unsigned* __restrict__ cursor,
                                               const int* __restrict__ ecol,
                                               const float* __restrict__ dinv,
                                               const float* __restrict__ b1,
                                               const float* __restrict__ W2,
                                               const __half2* __restrict__ h1h,
                                               __half2* __restrict__ h2h) {
    __shared__ float Ws[512];   // W2 [16][32]
    __shared__ float B1[16];
    int tid = threadIdx.x;
    Ws[tid] = W2[tid];
    Ws[tid + 256] = W2[tid + 256];
    if (tid < 16) B1[tid] = b1[tid];
    __syncthreads();
    int lane = tid & 63;
    int grp = lane >> 3, f2 = lane & 7;
    int node = blockIdx.x * 32 + (tid >> 6) * 8 + grp;
    unsigned s = node ? cursor[node - 1] : 0u;
    unsigned e = cursor[node];
    float2 acc = __half22float2(h1h[(size_t)node * 8 + f2]);   // self term
    for (unsigned j = s; j < e; j += 4) {
        bool v1 = j + 1 < e, v2 = j + 2 < e, v3 = j + 3 < e;
        int c0 = ecol[j];
        int c1 = v1 ? ecol[j + 1] : c0;
        int c2 = v2 ? ecol[j + 2] : c0;
        int c3 = v3 ? ecol[j + 3] : c0;
        float2 a0 = __half22float2(h1h[(size_t)c0 * 8 + f2]);
        float2 a1 = __half22float2(h1h[(size_t)c1 * 8 + f2]);
        float2 a2 = __half22float2(h1h[(size_t)c2 * 8 + f2]);
        float2 a3 = __half22float2(h1h[(size_t)c3 * 8 + f2]);
        float m1 = v1 ? 1.f : 0.f, m2 = v2 ? 1.f : 0.f, m3 = v3 ? 1.f : 0.f;
        acc.x += a0.x + m1 * a1.x + m2 * a2.x + m3 * a3.x;
        acc.y += a0.y + m1 * a1.y + m2 * a2.y + m3 * a3.y;
    }
    float dv = dinv[node];
    float r0 = fmaxf(acc.x * dv + B1[2 * f2], 0.f);
    float r1 = fmaxf(acc.y * dv + B1[2 * f2 + 1], 0.f);
    int gb = lane & 56;
    float rv[16];
    #pragma unroll
    for (int q = 0; q < 8; ++q) {
        rv[2 * q]     = __shfl(r0, gb + q);
        rv[2 * q + 1] = __shfl(r1, gb + q);
    }
    float o0x = 0.f, o0y = 0.f, o1x = 0.f, o1y = 0.f;
    #pragma unroll
    for (int q = 0; q < 16; ++q) {
        float r = rv[q];
        o0x += r * Ws[q * 32 + 2 * f2];
        o0y += r * Ws[q * 32 + 2 * f2 + 1];
        o1x += r * Ws[q * 32 + 2 * f2 + 16];
        o1y += r * Ws[q * 32 + 2 * f2 + 17];
    }
    h2h[(size_t)node * 16 + f2]     = __floats2half2_rn(o0x * dv, o0y * dv);
    h2h[(size_t)node * 16 + f2 + 8] = __floats2half2_rn(o1x * dv, o1y * dv);
}

// ---------- K6: gather layer 2 — node per 16-lane group (4 nodes/wave) ----------
__global__ __launch_bounds__(256) void k_gath2(const unsigned* __restrict__ cursor,
                                               const int* __restrict__ ecol,
                                               const float* __restrict__ dinv,
                                               const float* __restrict__ b2,
                                               const __half2* __restrict__ h2h,
                                               float* __restrict__ out2) {
    int tid = threadIdx.x;
    int lane = tid & 63;
    int grp = lane >> 4, f2 = lane & 15;
    int node = blockIdx.x * 16 + (tid >> 6) * 4 + grp;
    unsigned s = node ? cursor[node - 1] : 0u;
    unsigned e = cursor[node];
    float2 acc = __half22float2(h2h[(size_t)node * 16 + f2]);  // self term
    for (unsigned j = s; j < e; j += 4) {
        bool v1 = j + 1 < e, v2 = j + 2 < e, v3 = j + 3 < e;
        int c0 = ecol[j];
        int c1 = v1 ? ecol[j + 1] : c0;
        int c2 = v2 ? ecol[j + 2] : c0;
        int c3 = v3 ? ecol[j + 3] : c0;
        float2 a0 = __half22float2(h2h[(size_t)c0 * 16 + f2]);
        float2 a1 = __half22float2(h2h[(size_t)c1 * 16 + f2]);
        float2 a2 = __half22float2(h2h[(size_t)c2 * 16 + f2]);
        float2 a3 = __half22float2(h2h[(size_t)c3 * 16 + f2]);
        float m1 = v1 ? 1.f : 0.f, m2 = v2 ? 1.f : 0.f, m3 = v3 ? 1.f : 0.f;
        acc.x += a0.x + m1 * a1.x + m2 * a2.x + m3 * a3.x;
        acc.y += a0.y + m1 * a1.y + m2 * a2.y + m3 * a3.y;
    }
    float dv = dinv[node];
    float2 b = ((const float2*)b2)[f2];
    ((float2*)(out2 + (size_t)node * F2))[f2] =
        make_float2(acc.x * dv + b.x, acc.y * dv + b.y);
}

// ---------- K7: conv1d(32->64, k=3, pad 1) + global max ----------
#define NPB 256
__global__ __launch_bounds__(256) void k_conv(const float* __restrict__ h2f,
                                              const float* __restrict__ cw,
                                              unsigned* __restrict__ pool) {
    __shared__ float Hs[NPB + 2][33];
    __shared__ float Wt[3 * 32 * 64];
    __shared__ float4 Ms[4][16];
    int tid = threadIdx.x;
    int base = blockIdx.x * NPB;
    for (int idx = tid; idx < 6144; idx += 256) {
        int o = idx / 96, r = idx % 96, ci = r / 3, k = r % 3;
        Wt[(k * 32 + ci) * 64 + o] = cw[idx];
    }
    for (int idx = tid; idx < (NPB + 2) * 8; idx += 256) {
        int j = idx >> 3, c4 = (idx & 7) << 2;
        int g = base + j - 1;
        float4 v = make_float4(0.f, 0.f, 0.f, 0.f);
        if (g >= 0 && g < NN) v = *(const float4*)(h2f + (size_t)g * F2 + c4);
        Hs[j][c4 + 0] = v.x;
        Hs[j][c4 + 1] = v.y;
        Hs[j][c4 + 2] = v.z;
        Hs[j][c4 + 3] = v.w;
    }
    __syncthreads();

    int o4 = (tid & 15) * 4;
    int ng = tid >> 4;
    float4 acc[16] = {};
    for (int ci = 0; ci < 32; ++ci) {
        float h[18];
        #pragma unroll
        for (int j = 0; j < 18; ++j) h[j] = Hs[ng * 16 + j][ci];
        #pragma unroll
        for (int k = 0; k < 3; ++k) {
            float4 w = *(const float4*)&Wt[(k * 32 + ci) * 64 + o4];
            #pragma unroll
            for (int i = 0; i < 16; ++i) {
                float hv = h[i + k];
                acc[i].x += hv * w.x;
                acc[i].y += hv * w.y;
                acc[i].z += hv * w.z;
                acc[i].w += hv * w.w;
            }
        }
    }
    const float NI = -3.0e38f;
    float4 m4 = make_float4(NI, NI, NI, NI);
    #pragma unroll
    for (int i = 0; i < 16; ++i) {
        if (base + ng * 16 + i < NN) {
            m4.x = fmaxf(m4.x, acc[i].x);
            m4.y = fmaxf(m4.y, acc[i].y);
            m4.z = fmaxf(m4.z, acc[i].z);
            m4.w = fmaxf(m4.w, acc[i].w);
        }
    }
    #pragma unroll
    for (int off = 16; off <= 32; off <<= 1) {
        m4.x = fmaxf(m4.x, __shfl_xor(m4.x, off));
        m4.y = fmaxf(m4.y, __shfl_xor(m4.y, off));
        m4.z = fmaxf(m4.z, __shfl_xor(m4.z, off));
        m4.w = fmaxf(m4.w, __shfl_xor(m4.w, off));
    }
    int lane = tid & 63, wv = tid >> 6;
    if (lane < 16) Ms[wv][lane] = m4;
    __syncthreads();
    if (tid < 16) {
        float4 a = Ms[0][tid], b = Ms[1][tid], c = Ms[2][tid], d = Ms[3][tid];
        a.x = fmaxf(fmaxf(a.x, b.x), fmaxf(c.x, d.x));
        a.y = fmaxf(fmaxf(a.y, b.y), fmaxf(c.y, d.y));
        a.z = fmaxf(fmaxf(a.z, b.z), fmaxf(c.z, d.z));
        a.w = fmaxf(fmaxf(a.w, b.w), fmaxf(c.w, d.w));
        int o = tid * 4;
        atomicMax(&pool[o + 0], enc_f(a.x));
        atomicMax(&pool[o + 1], enc_f(a.y));
        atomicMax(&pool[o + 2], enc_f(a.z));
        atomicMax(&pool[o + 3], enc_f(a.w));
    }
}

// ---------- K8: out = (pooled + conv_b) @ fc_w^T + fc_b ----------
__global__ void k_fc(const unsigned* __restrict__ pool, const float* __restrict__ cb,
                     const float* __restrict__ fw, const float* __restrict__ fb,
                     float* __restrict__ out) {
    __shared__ float P[64];
    int tid = threadIdx.x;
    if (tid < 64) P[tid] = dec_f(pool[tid]) + cb[tid];
    __syncthreads();
    int j = blockIdx.x * 256 + tid;
    if (j >= NC) return;
    float s = fb[j];
    const float4* wr = (const float4*)(fw + (size_t)j * CO);
    #pragma unroll
    for (int c = 0; c < 16; ++c) {
        float4 w = wr[c];
        s += P[c * 4 + 0] * w.x + P[c * 4 + 1] * w.y +
             P[c * 4 + 2] * w.z + P[c * 4 + 3] * w.w;
    }
    out[j] = s;
}

extern "C" void kernel_launch(void* const* d_in, const int* in_sizes, int n_in,
                              void* d_out, int out_size, void* d_ws, size_t ws_size,
                              hipStream_t stream) {
    const float* x  = (const float*)d_in[0];
    const int*   ei = (const int*)d_in[1];
    const float* W1 = (const float*)d_in[2];
    const float* b1 = (const float*)d_in[3];
    const float* W2 = (const float*)d_in[4];
    const float* b2 = (const float*)d_in[5];
    const float* cw = (const float*)d_in[6];
    const float* cb = (const float*)d_in[7];
    const float* fw = (const float*)d_in[8];
    const float* fb = (const float*)d_in[9];

    float* ws = (float*)d_ws;
    float*    dinv   = ws + OFF_DINV;
    unsigned* cursor = (unsigned*)(ws + OFF_CUR);
    unsigned* deg    = (unsigned*)(ws + OFF_DEG);
    int*      ecol   = (int*)(ws + OFF_ECOL);
    unsigned* pc     = (unsigned*)(ws + OFF_MISC);
    unsigned* pcur   = pc + 256;
    unsigned* pbase  = pc + 512;
    unsigned* pcnt8  = pc + 520;
    unsigned* pool   = pc + 528;
    unsigned* bsum   = pc + 592;
    int*      dpart  = (int*)(ws + OFF_DPART);
    int*      spart  = (int*)(ws + OFF_SPART);
    unsigned* hist   = (unsigned*)(ws + OFF_HIST);
    __half2*  h1h    = (__half2*)(ws + OFF_H1S);
    __half2*  h2h    = (__half2*)(ws + OFF_H2S);
    float*    out2   = ws + OFF_OUT2;

    hipMemsetAsync(pc, 0, 256 * 4, stream);
    hipMemsetAsync(pool, 0, 64 * 4, stream);

    k_pcount <<<NE / (256 * BK), 256, 0, stream>>>(ei, pc);            // 2500 blocks
    k_pscan  <<<1, 256, 0, stream>>>(pc, pcur, pbase, pcnt8);
    k_bucket <<<NE / (256 * BK), 256, 0, stream>>>(ei, pcur, dpart, spart);
    k_hist   <<<CH * NPART, 256, 0, stream>>>(pbase, pcnt8, dpart, hist);  // 128 blocks
    k_colscan<<<NBLK, 256, 0, stream>>>(hist, deg);
    k_bsum   <<<NBLK, 256, 0, stream>>>(deg, bsum);
    k_bscan  <<<1, 512, 0, stream>>>(bsum);
    k_cscan  <<<NBLK, 256, 0, stream>>>(deg, bsum, cursor, dinv);
    k_place  <<<CH * NPART, 256, 0, stream>>>(pbase, pcnt8, dpart, spart, hist, cursor, ecol);
    k_gemm1  <<<GBLK, 64, 0, stream>>>(x, W1, dinv, h1h);                  // 1563 blocks
    k_gathm  <<<NN / 32, 256, 0, stream>>>(cursor, ecol, dinv, b1, W2, h1h, h2h);   // 3125
    k_gath2  <<<NN / 16, 256, 0, stream>>>(cursor, ecol, dinv, b2, h2h, out2);      // 6250
    k_conv   <<<(NN + NPB - 1) / NPB, 256, 0, stream>>>(out2, cw, pool);
    k_fc     <<<4, 256, 0, stream>>>(pool, cb, fw, fb, (float*)d_out);
}

// Round 14
// 312.267 us; speedup vs baseline: 1.4788x; 1.4788x over previous
//
#include <hip/hip_runtime.h>
#include <hip/hip_bf16.h>
#include <hip/hip_fp16.h>

#define NN 100000
#define NE 3200000
#define FIN 256
#define F1 16
#define F2 32
#define CO 64
#define NC 1000
#define NBLK 391   /* ceil(NN/256) */
#define GBLK 1563  /* ceil(NN/64) gemm1 grid (64-thread blocks, 1 row/thread) */
#define NPART 8
#define NGRP 32    /* counter split per bin */
#define PSZ 12500  /* NN / NPART */
#define BK 20      /* edges per thread in pcount/bucket; 625 blocks * 256 * 20 = NE */
#define CH 16      /* chunks per partition for hist/place */

// workspace layout (float offsets) — total 11,502,080 floats = 46.0 MB
#define OFF_DINV 0
#define OFF_CUR  100352
#define OFF_DEG  200704
#define OFF_ECOL 301056
#define OFF_MISC 3501056   /* pc[256], pcur[256]@256, pbase[8]@512, pcnt8[8]@520,
                              pool[64]@528, bsum[391]@592 — ends 983 < 1024 */
#define OFF_DPART 3502080
#define OFF_SPART 6702080
#define OFF_HIST 9902080   /* u32[NPART*CH*PSZ] = 1.6M */
#define OFF_H1S  3502080   /* fp16, 800K floats; overlays dpart (dead after place) */
#define OFF_H2S  6702080   /* fp16, 1.6M floats (ends 8302080); overlays spart (dead after place) */
#define OFF_OUT2 3502080   /* f32 3.2M floats: 3502080..6702080 — overlays h1h+dpart (dead
                              after gathm), ends exactly at h2h start. MUST NOT cross 6702080. */

__device__ __forceinline__ unsigned enc_f(float f) {
    unsigned u = __float_as_uint(f);
    return (u & 0x80000000u) ? ~u : (u | 0x80000000u);
}
__device__ __forceinline__ float dec_f(unsigned u) {
    return (u & 0x80000000u) ? __uint_as_float(u & 0x7fffffffu) : __uint_as_float(~u);
}

// ---------- K0a: partition edge counts, block-aggregated (8 atomics/block) ----------
__global__ __launch_bounds__(256) void k_pcount(const int* __restrict__ ei,
                                                unsigned* __restrict__ pc) {
    __shared__ unsigned wcnt[4][8];
    int t = threadIdx.x, lane = t & 63, w = t >> 6;
    int g = blockIdx.x & (NGRP - 1);
    int base = blockIdx.x * (256 * BK) + t;
    unsigned cnt = 0;
    #pragma unroll
    for (int k = 0; k < BK; ++k) {
        int bin = (unsigned)ei[NE + base + k * 256] / PSZ;
        #pragma unroll
        for (int b = 0; b < 8; ++b) {
            unsigned long long m = __ballot(bin == b);
            if (lane == b) cnt += (unsigned)__popcll(m);
        }
    }
    if (lane < 8) wcnt[w][lane] = cnt;
    __syncthreads();
    if (t < 8)
        atomicAdd(&pc[t * NGRP + g],
                  wcnt[0][t] + wcnt[1][t] + wcnt[2][t] + wcnt[3][t]);
}

// ---------- K0b: scan 256 split counters (bin-major) -> pcur, pbase, pcnt8 ----------
__global__ __launch_bounds__(256) void k_pscan(const unsigned* __restrict__ pc,
                                               unsigned* __restrict__ pcur,
                                               unsigned* __restrict__ pbase,
                                               unsigned* __restrict__ pcnt8) {
    __shared__ unsigned S[256];
    int t = threadIdx.x;
    unsigned v = pc[t];
    S[t] = v;
    __syncthreads();
    for (int off = 1; off < 256; off <<= 1) {
        unsigned u = (t >= off) ? S[t - off] : 0u;
        __syncthreads();
        S[t] += u;
        __syncthreads();
    }
    pcur[t] = S[t] - v;                       // exclusive prefix
    if ((t & 31) == 0) pbase[t >> 5] = S[t] - v;
    if ((t & 31) == 31) {
        unsigned start = S[t & ~31] - pc[t & ~31];
        pcnt8[t >> 5] = S[t] - start;
    }
}

// ---------- K0c: bucket edges, block-aggregated reservation (8 atomics/block) ----------
__global__ __launch_bounds__(256) void k_bucket(const int* __restrict__ ei,
                                                unsigned* __restrict__ pcur,
                                                int* __restrict__ dpart,
                                                int* __restrict__ spart) {
    __shared__ unsigned wcnt[4][8];
    __shared__ unsigned woff[4][8];
    int t = threadIdx.x, lane = t & 63, w = t >> 6;
    int g = blockIdx.x & (NGRP - 1);
    int base = blockIdx.x * (256 * BK) + t;
    int dst[BK], src[BK];
    #pragma unroll
    for (int k = 0; k < BK; ++k) {
        dst[k] = ei[NE + base + k * 256];
        src[k] = ei[base + k * 256];
    }
    unsigned long long lt = (lane == 63) ? 0x7fffffffffffffffull
                                         : ((1ull << lane) - 1ull);
    // sweep 1: per-wave per-bin counts (lane b tracks bin b)
    unsigned cnt = 0;
    #pragma unroll
    for (int k = 0; k < BK; ++k) {
        int bin = (unsigned)dst[k] / PSZ;
        #pragma unroll
        for (int b = 0; b < 8; ++b) {
            unsigned long long m = __ballot(bin == b);
            if (lane == b) cnt += (unsigned)__popcll(m);
        }
    }
    if (lane < 8) wcnt[w][lane] = cnt;
    __syncthreads();
    if (t < 8) {
        unsigned c0 = wcnt[0][t], c1 = wcnt[1][t], c2 = wcnt[2][t], c3 = wcnt[3][t];
        unsigned b = atomicAdd(&pcur[t * NGRP + g], c0 + c1 + c2 + c3);
        woff[0][t] = b;
        woff[1][t] = b + c0;
        woff[2][t] = b + c0 + c1;
        woff[3][t] = b + c0 + c1 + c2;
    }
    __syncthreads();
    unsigned run = (lane < 8) ? woff[w][lane] : 0u;
    // sweep 2: place
    #pragma unroll
    for (int k = 0; k < BK; ++k) {
        int bin = (unsigned)dst[k] / PSZ;
        unsigned long long mym = 0;
        unsigned myrun = 0;
        #pragma unroll
        for (int b = 0; b < 8; ++b) {
            unsigned long long m = __ballot(bin == b);
            unsigned r = __shfl(run, b);
            if (bin == b) { mym = m; myrun = r; }
            if (lane == b) run += (unsigned)__popcll(m);
        }
        unsigned pos = myrun + (unsigned)__popcll(mym & lt);
        dpart[pos] = dst[k];
        spart[pos] = src[k];
    }
}

// ---------- K0d: per-chunk LDS histograms -> hist[p][c][i] ----------
__global__ __launch_bounds__(256) void k_hist(const unsigned* __restrict__ pbase,
                                              const unsigned* __restrict__ pcnt,
                                              const int* __restrict__ dpart,
                                              unsigned* __restrict__ hist) {
    __shared__ unsigned lh[PSZ];
    int p = blockIdx.x & 7;
    int c = blockIdx.x >> 3;               // 0..CH-1
    int t = threadIdx.x;
    for (int i = t; i < PSZ; i += 256) lh[i] = 0;
    __syncthreads();
    unsigned s = pbase[p], n = pcnt[p];
    unsigned c0 = s + (unsigned)(((unsigned long long)n * c) / CH);
    unsigned c1 = s + (unsigned)(((unsigned long long)n * (c + 1)) / CH);
    int pb = p * PSZ;
    for (unsigned j = c0 + t; j < c1; j += 256)
        atomicAdd(&lh[dpart[j] - pb], 1u);
    __syncthreads();
    unsigned* hrow = hist + (unsigned)(p * CH + c) * PSZ;
    for (int i = t; i < PSZ; i += 256) hrow[i] = lh[i];
}

// ---------- K0e: scan chunk counts per bin -> chunk bases (in place) + deg ----------
__global__ __launch_bounds__(256) void k_colscan(unsigned* __restrict__ hist,
                                                 unsigned* __restrict__ deg) {
    int gid = blockIdx.x * 256 + threadIdx.x;
    if (gid >= NN) return;
    int p = gid / PSZ, i = gid % PSZ;
    unsigned run = 0;
    #pragma unroll
    for (int c = 0; c < CH; ++c) {
        unsigned idx = (unsigned)(p * CH + c) * PSZ + i;
        unsigned v = hist[idx];
        hist[idx] = run;
        run += v;
    }
    deg[gid] = run;
}

// ---------- K1a: per-block degree sums ----------
__global__ void k_bsum(const unsigned* __restrict__ deg, unsigned* __restrict__ bsum) {
    __shared__ unsigned W[4];
    int t = threadIdx.x;
    int i = blockIdx.x * 256 + t;
    unsigned d = (i < NN) ? deg[i] : 0u;
    #pragma unroll
    for (int off = 1; off < 64; off <<= 1) d += __shfl_xor(d, off);
    if ((t & 63) == 0) W[t >> 6] = d;
    __syncthreads();
    if (t == 0) bsum[blockIdx.x] = W[0] + W[1] + W[2] + W[3];
}

// ---------- K1b: exclusive scan of block sums (1 block) ----------
__global__ __launch_bounds__(512) void k_bscan(unsigned* __restrict__ bsum) {
    __shared__ unsigned S[512];
    int t = threadIdx.x;
    unsigned v = (t < NBLK) ? bsum[t] : 0u;
    S[t] = v;
    __syncthreads();
    for (int off = 1; off < 512; off <<= 1) {
        unsigned u = (t >= off) ? S[t - off] : 0u;
        __syncthreads();
        S[t] += u;
        __syncthreads();
    }
    if (t < NBLK) bsum[t] = S[t] - v;   // exclusive prefix
}

// ---------- K1c: per-block scan -> cursor[i] = rowptr[i+1] (inclusive), dinv ----------
__global__ void k_cscan(const unsigned* __restrict__ deg, const unsigned* __restrict__ bsum,
                        unsigned* __restrict__ cursor, float* __restrict__ dinv) {
    __shared__ unsigned S[256];
    int t = threadIdx.x;
    int i = blockIdx.x * 256 + t;
    unsigned d = (i < NN) ? deg[i] : 0u;
    S[t] = d;
    __syncthreads();
    for (int off = 1; off < 256; off <<= 1) {
        unsigned u = (t >= off) ? S[t - off] : 0u;
        __syncthreads();
        S[t] += u;
        __syncthreads();
    }
    if (i < NN) {
        cursor[i] = bsum[blockIdx.x] + S[t];       // inclusive = rowptr[i+1]
        dinv[i] = rsqrtf((float)(d + 1u));
    }
}

// ---------- K2: place edges via LDS cursors (no global atomics) ----------
__global__ __launch_bounds__(256) void k_place(const unsigned* __restrict__ pbase,
                                               const unsigned* __restrict__ pcnt,
                                               const int* __restrict__ dpart,
                                               const int* __restrict__ spart,
                                               const unsigned* __restrict__ hist,
                                               const unsigned* __restrict__ cursor,
                                               int* __restrict__ ecol) {
    __shared__ unsigned lcur[PSZ];
    int p = blockIdx.x & 7;
    int c = blockIdx.x >> 3;
    int t = threadIdx.x;
    int pb = p * PSZ;
    const unsigned* hrow = hist + (unsigned)(p * CH + c) * PSZ;
    for (int i = t; i < PSZ; i += 256) {
        int gi = pb + i;
        unsigned rowstart = gi ? cursor[gi - 1] : 0u;
        lcur[i] = rowstart + hrow[i];
    }
    __syncthreads();
    unsigned s = pbase[p], n = pcnt[p];
    unsigned c0 = s + (unsigned)(((unsigned long long)n * c) / CH);
    unsigned c1 = s + (unsigned)(((unsigned long long)n * (c + 1)) / CH);
    for (unsigned j = c0 + t; j < c1; j += 256) {
        int dst = dpart[j];
        int src = spart[j];
        unsigned pos = atomicAdd(&lcur[dst - pb], 1u);
        ecol[pos] = src;
    }
}

// ---------- K3: h1h = fp16((X @ W1) * dinv[row]) — thread-per-row, no barriers ----------
__device__ __forceinline__ void fma16(float xk, const float4* __restrict__ w4,
                                      float* __restrict__ acc) {
    float4 a = w4[0], b = w4[1], c = w4[2], d = w4[3];
    acc[0]  += xk * a.x; acc[1]  += xk * a.y; acc[2]  += xk * a.z; acc[3]  += xk * a.w;
    acc[4]  += xk * b.x; acc[5]  += xk * b.y; acc[6]  += xk * b.z; acc[7]  += xk * b.w;
    acc[8]  += xk * c.x; acc[9]  += xk * c.y; acc[10] += xk * c.z; acc[11] += xk * c.w;
    acc[12] += xk * d.x; acc[13] += xk * d.y; acc[14] += xk * d.z; acc[15] += xk * d.w;
}

__global__ __launch_bounds__(64) void k_gemm1(const float* __restrict__ X,
                                              const float* __restrict__ W1,
                                              const float* __restrict__ dinv,
                                              __half2* __restrict__ h1h) {
    __shared__ float Ws[4096];   // W1 [256][16]
    int t = threadIdx.x;
    {
        float4* Ws4 = (float4*)Ws;
        const float4* W14 = (const float4*)W1;
        #pragma unroll
        for (int i = 0; i < 16; ++i) Ws4[t + i * 64] = W14[t + i * 64];
    }
    __syncthreads();
    int row = blockIdx.x * 64 + t;
    if (row >= NN) return;

    const float4* xr = (const float4*)(X + (size_t)row * FIN);
    float acc[16] = {};
    float4 A0 = xr[0], A1 = xr[1], A2 = xr[2], A3 = xr[3];

#define DO4(xq, kb) \
    fma16((xq).x, (const float4*)&Ws[(kb) * 16],        acc); \
    fma16((xq).y, (const float4*)&Ws[((kb) + 1) * 16],  acc); \
    fma16((xq).z, (const float4*)&Ws[((kb) + 2) * 16],  acc); \
    fma16((xq).w, (const float4*)&Ws[((kb) + 3) * 16],  acc);

    #pragma unroll 1
    for (int c = 0; c < 8; ++c) {
        int kb = c * 32;
        float4 B0 = xr[c * 8 + 4], B1 = xr[c * 8 + 5],
               B2 = xr[c * 8 + 6], B3 = xr[c * 8 + 7];
        DO4(A0, kb);      DO4(A1, kb + 4);
        DO4(A2, kb + 8);  DO4(A3, kb + 12);
        if (c < 7) {
            A0 = xr[c * 8 + 8];  A1 = xr[c * 8 + 9];
            A2 = xr[c * 8 + 10]; A3 = xr[c * 8 + 11];
        }
        DO4(B0, kb + 16); DO4(B1, kb + 20);
        DO4(B2, kb + 24); DO4(B3, kb + 28);
    }
#undef DO4

    float dv = dinv[row];
    union { __half2 h[8]; uint4 u[2]; } pk;
    #pragma unroll
    for (int o = 0; o < 8; ++o)
        pk.h[o] = __floats2half2_rn(acc[2 * o] * dv, acc[2 * o + 1] * dv);
    uint4* dst = (uint4*)(h1h + (size_t)row * 8);
    dst[0] = pk.u[0];
    dst[1] = pk.u[1];
}

// ---------- K4: fused gather-1 + gemm2 — node per 8-lane group (8 nodes/wave) ----------
__global__ __launch_bounds__(256) void k_gathm(const unsigned* __restrict__ cursor,
                                               const int* __restrict__ ecol,
                                               const float* __restrict__ dinv,
                                               const float* __restrict__ b1,
                                               const float* __restrict__ W2,
                                               const __half2* __restrict__ h1h,
                                               __half2* __restrict__ h2h) {
    __shared__ float Ws[512];   // W2 [16][32]
    __shared__ float B1[16];
    int tid = threadIdx.x;
    Ws[tid] = W2[tid];
    Ws[tid + 256] = W2[tid + 256];
    if (tid < 16) B1[tid] = b1[tid];
    __syncthreads();
    int lane = tid & 63;
    int grp = lane >> 3, f2 = lane & 7;
    int node = blockIdx.x * 32 + (tid >> 6) * 8 + grp;
    unsigned s = node ? cursor[node - 1] : 0u;
    unsigned e = cursor[node];
    float2 acc = __half22float2(h1h[(size_t)node * 8 + f2]);   // self term
    for (unsigned j = s; j < e; j += 4) {
        bool v1 = j + 1 < e, v2 = j + 2 < e, v3 = j + 3 < e;
        int c0 = ecol[j];
        int c1 = v1 ? ecol[j + 1] : c0;
        int c2 = v2 ? ecol[j + 2] : c0;
        int c3 = v3 ? ecol[j + 3] : c0;
        float2 a0 = __half22float2(h1h[(size_t)c0 * 8 + f2]);
        float2 a1 = __half22float2(h1h[(size_t)c1 * 8 + f2]);
        float2 a2 = __half22float2(h1h[(size_t)c2 * 8 + f2]);
        float2 a3 = __half22float2(h1h[(size_t)c3 * 8 + f2]);
        float m1 = v1 ? 1.f : 0.f, m2 = v2 ? 1.f : 0.f, m3 = v3 ? 1.f : 0.f;
        acc.x += a0.x + m1 * a1.x + m2 * a2.x + m3 * a3.x;
        acc.y += a0.y + m1 * a1.y + m2 * a2.y + m3 * a3.y;
    }
    float dv = dinv[node];
    float r0 = fmaxf(acc.x * dv + B1[2 * f2], 0.f);
    float r1 = fmaxf(acc.y * dv + B1[2 * f2 + 1], 0.f);
    int gb = lane & 56;
    float rv[16];
    #pragma unroll
    for (int q = 0; q < 8; ++q) {
        rv[2 * q]     = __shfl(r0, gb + q);
        rv[2 * q + 1] = __shfl(r1, gb + q);
    }
    float o0x = 0.f, o0y = 0.f, o1x = 0.f, o1y = 0.f;
    #pragma unroll
    for (int q = 0; q < 16; ++q) {
        float r = rv[q];
        o0x += r * Ws[q * 32 + 2 * f2];
        o0y += r * Ws[q * 32 + 2 * f2 + 1];
        o1x += r * Ws[q * 32 + 2 * f2 + 16];
        o1y += r * Ws[q * 32 + 2 * f2 + 17];
    }
    h2h[(size_t)node * 16 + f2]     = __floats2half2_rn(o0x * dv, o0y * dv);
    h2h[(size_t)node * 16 + f2 + 8] = __floats2half2_rn(o1x * dv, o1y * dv);
}

// ---------- K6: gather layer 2 — node per 16-lane group (4 nodes/wave) ----------
__global__ __launch_bounds__(256) void k_gath2(const unsigned* __restrict__ cursor,
                                               const int* __restrict__ ecol,
                                               const float* __restrict__ dinv,
                                               const float* __restrict__ b2,
                                               const __half2* __restrict__ h2h,
                                               float* __restrict__ out2) {
    int tid = threadIdx.x;
    int lane = tid & 63;
    int grp = lane >> 4, f2 = lane & 15;
    int node = blockIdx.x * 16 + (tid >> 6) * 4 + grp;
    unsigned s = node ? cursor[node - 1] : 0u;
    unsigned e = cursor[node];
    float2 acc = __half22float2(h2h[(size_t)node * 16 + f2]);  // self term
    for (unsigned j = s; j < e; j += 4) {
        bool v1 = j + 1 < e, v2 = j + 2 < e, v3 = j + 3 < e;
        int c0 = ecol[j];
        int c1 = v1 ? ecol[j + 1] : c0;
        int c2 = v2 ? ecol[j + 2] : c0;
        int c3 = v3 ? ecol[j + 3] : c0;
        float2 a0 = __half22float2(h2h[(size_t)c0 * 16 + f2]);
        float2 a1 = __half22float2(h2h[(size_t)c1 * 16 + f2]);
        float2 a2 = __half22float2(h2h[(size_t)c2 * 16 + f2]);
        float2 a3 = __half22float2(h2h[(size_t)c3 * 16 + f2]);
        float m1 = v1 ? 1.f : 0.f, m2 = v2 ? 1.f : 0.f, m3 = v3 ? 1.f : 0.f;
        acc.x += a0.x + m1 * a1.x + m2 * a2.x + m3 * a3.x;
        acc.y += a0.y + m1 * a1.y + m2 * a2.y + m3 * a3.y;
    }
    float dv = dinv[node];
    float2 b = ((const float2*)b2)[f2];
    ((float2*)(out2 + (size_t)node * F2))[f2] =
        make_float2(acc.x * dv + b.x, acc.y * dv + b.y);
}

// ---------- K7: conv1d(32->64, k=3, pad 1) + global max ----------
#define NPB 256
__global__ __launch_bounds__(256) void k_conv(const float* __restrict__ h2f,
                                              const float* __restrict__ cw,
                                              unsigned* __restrict__ pool) {
    __shared__ float Hs[NPB + 2][33];
    __shared__ float Wt[3 * 32 * 64];
    __shared__ float4 Ms[4][16];
    int tid = threadIdx.x;
    int base = blockIdx.x * NPB;
    for (int idx = tid; idx < 6144; idx += 256) {
        int o = idx / 96, r = idx % 96, ci = r / 3, k = r % 3;
        Wt[(k * 32 + ci) * 64 + o] = cw[idx];
    }
    for (int idx = tid; idx < (NPB + 2) * 8; idx += 256) {
        int j = idx >> 3, c4 = (idx & 7) << 2;
        int g = base + j - 1;
        float4 v = make_float4(0.f, 0.f, 0.f, 0.f);
        if (g >= 0 && g < NN) v = *(const float4*)(h2f + (size_t)g * F2 + c4);
        Hs[j][c4 + 0] = v.x;
        Hs[j][c4 + 1] = v.y;
        Hs[j][c4 + 2] = v.z;
        Hs[j][c4 + 3] = v.w;
    }
    __syncthreads();

    int o4 = (tid & 15) * 4;
    int ng = tid >> 4;
    float4 acc[16] = {};
    for (int ci = 0; ci < 32; ++ci) {
        float h[18];
        #pragma unroll
        for (int j = 0; j < 18; ++j) h[j] = Hs[ng * 16 + j][ci];
        #pragma unroll
        for (int k = 0; k < 3; ++k) {
            float4 w = *(const float4*)&Wt[(k * 32 + ci) * 64 + o4];
            #pragma unroll
            for (int i = 0; i < 16; ++i) {
                float hv = h[i + k];
                acc[i].x += hv * w.x;
                acc[i].y += hv * w.y;
                acc[i].z += hv * w.z;
                acc[i].w += hv * w.w;
            }
        }
    }
    const float NI = -3.0e38f;
    float4 m4 = make_float4(NI, NI, NI, NI);
    #pragma unroll
    for (int i = 0; i < 16; ++i) {
        if (base + ng * 16 + i < NN) {
            m4.x = fmaxf(m4.x, acc[i].x);
            m4.y = fmaxf(m4.y, acc[i].y);
            m4.z = fmaxf(m4.z, acc[i].z);
            m4.w = fmaxf(m4.w, acc[i].w);
        }
    }
    #pragma unroll
    for (int off = 16; off <= 32; off <<= 1) {
        m4.x = fmaxf(m4.x, __shfl_xor(m4.x, off));
        m4.y = fmaxf(m4.y, __shfl_xor(m4.y, off));
        m4.z = fmaxf(m4.z, __shfl_xor(m4.z, off));
        m4.w = fmaxf(m4.w, __shfl_xor(m4.w, off));
    }
    int lane = tid & 63, wv = tid >> 6;
    if (lane < 16) Ms[wv][lane] = m4;
    __syncthreads();
    if (tid < 16) {
        float4 a = Ms[0][tid], b = Ms[1][tid], c = Ms[2][tid], d = Ms[3][tid];
        a.x = fmaxf(fmaxf(a.x, b.x), fmaxf(c.x, d.x));
        a.y = fmaxf(fmaxf(a.y, b.y), fmaxf(c.y, d.y));
        a.z = fmaxf(fmaxf(a.z, b.z), fmaxf(c.z, d.z));
        a.w = fmaxf(fmaxf(a.w, b.w), fmaxf(c.w, d.w));
        int o = tid * 4;
        atomicMax(&pool[o + 0], enc_f(a.x));
        atomicMax(&pool[o + 1], enc_f(a.y));
        atomicMax(&pool[o + 2], enc_f(a.z));
        atomicMax(&pool[o + 3], enc_f(a.w));
    }
}

// ---------- K8: out = (pooled + conv_b) @ fc_w^T + fc_b ----------
__global__ void k_fc(const unsigned* __restrict__ pool, const float* __restrict__ cb,
                     const float* __restrict__ fw, const float* __restrict__ fb,
                     float* __restrict__ out) {
    __shared__ float P[64];
    int tid = threadIdx.x;
    if (tid < 64) P[tid] = dec_f(pool[tid]) + cb[tid];
    __syncthreads();
    int j = blockIdx.x * 256 + tid;
    if (j >= NC) return;
    float s = fb[j];
    const float4* wr = (const float4*)(fw + (size_t)j * CO);
    #pragma unroll
    for (int c = 0; c < 16; ++c) {
        float4 w = wr[c];
        s += P[c * 4 + 0] * w.x + P[c * 4 + 1] * w.y +
             P[c * 4 + 2] * w.z + P[c * 4 + 3] * w.w;
    }
    out[j] = s;
}

extern "C" void kernel_launch(void* const* d_in, const int* in_sizes, int n_in,
                              void* d_out, int out_size, void* d_ws, size_t ws_size,
                              hipStream_t stream) {
    const float* x  = (const float*)d_in[0];
    const int*   ei = (const int*)d_in[1];
    const float* W1 = (const float*)d_in[2];
    const float* b1 = (const float*)d_in[3];
    const float* W2 = (const float*)d_in[4];
    const float* b2 = (const float*)d_in[5];
    const float* cw = (const float*)d_in[6];
    const float* cb = (const float*)d_in[7];
    const float* fw = (const float*)d_in[8];
    const float* fb = (const float*)d_in[9];

    float* ws = (float*)d_ws;
    float*    dinv   = ws + OFF_DINV;
    unsigned* cursor = (unsigned*)(ws + OFF_CUR);
    unsigned* deg    = (unsigned*)(ws + OFF_DEG);
    int*      ecol   = (int*)(ws + OFF_ECOL);
    unsigned* pc     = (unsigned*)(ws + OFF_MISC);
    unsigned* pcur   = pc + 256;
    unsigned* pbase  = pc + 512;
    unsigned* pcnt8  = pc + 520;
    unsigned* pool   = pc + 528;
    unsigned* bsum   = pc + 592;
    int*      dpart  = (int*)(ws + OFF_DPART);
    int*      spart  = (int*)(ws + OFF_SPART);
    unsigned* hist   = (unsigned*)(ws + OFF_HIST);
    __half2*  h1h    = (__half2*)(ws + OFF_H1S);
    __half2*  h2h    = (__half2*)(ws + OFF_H2S);
    float*    out2   = ws + OFF_OUT2;

    hipMemsetAsync(pc, 0, 256 * 4, stream);
    hipMemsetAsync(pool, 0, 64 * 4, stream);

    k_pcount <<<NE / (256 * BK), 256, 0, stream>>>(ei, pc);            // 625 blocks
    k_pscan  <<<1, 256, 0, stream>>>(pc, pcur, pbase, pcnt8);
    k_bucket <<<NE / (256 * BK), 256, 0, stream>>>(ei, pcur, dpart, spart);
    k_hist   <<<CH * NPART, 256, 0, stream>>>(pbase, pcnt8, dpart, hist);  // 128 blocks
    k_colscan<<<NBLK, 256, 0, stream>>>(hist, deg);
    k_bsum   <<<NBLK, 256, 0, stream>>>(deg, bsum);
    k_bscan  <<<1, 512, 0, stream>>>(bsum);
    k_cscan  <<<NBLK, 256, 0, stream>>>(deg, bsum, cursor, dinv);
    k_place  <<<CH * NPART, 256, 0, stream>>>(pbase, pcnt8, dpart, spart, hist, cursor, ecol);
    k_gemm1  <<<GBLK, 64, 0, stream>>>(x, W1, dinv, h1h);                  // 1563 blocks
    k_gathm  <<<NN / 32, 256, 0, stream>>>(cursor, ecol, dinv, b1, W2, h1h, h2h);   // 3125
    k_gath2  <<<NN / 16, 256, 0, stream>>>(cursor, ecol, dinv, b2, h2h, out2);      // 6250
    k_conv   <<<(NN + NPB - 1) / NPB, 256, 0, stream>>>(out2, cw, pool);
    k_fc     <<<4, 256, 0, stream>>>(pool, cb, fw, fb, (float*)d_out);
}

// Round 15
// 274.607 us; speedup vs baseline: 1.6817x; 1.1371x over previous
//
#include <hip/hip_runtime.h>
#include <hip/hip_bf16.h>
#include <hip/hip_fp16.h>

#define NN 100000
#define NE 3200000
#define FIN 256
#define F1 16
#define F2 32
#define CO 64
#define NC 1000
#define NBLK 391   /* ceil(NN/256) */
#define GBLK 1563  /* ceil(NN/64) gemm1 grid (64-thread blocks, 1 row/thread) */
#define NPART 8
#define NGRP 32    /* sub-segments (groups) per partition */
#define CAPG 16384 /* fixed capacity per (partition,group) sub-segment */
#define PSZ 12500  /* NN / NPART */
#define BK 20      /* edges per thread in bucket; 625 blocks * 256 * 20 = NE */

// workspace layout (float offsets) — total 15,090,688 floats = 60.4 MB
#define OFF_DINV 0
#define OFF_CUR  100352
#define OFF_DEG  200704
#define OFF_ECOL 301056
#define OFF_MISC 3501056    /* pcur[256]@0, pool[64]@256, bsum[391]@320 (ends 711) */
#define OFF_DPART 3502080   /* 8*32*16384 = 4,194,304 -> ends 7,696,384 */
#define OFF_SPART 7696384   /* 4,194,304 -> ends 11,890,688 */
#define OFF_HIST 11890688   /* u32[8*32*12500] = 3.2M -> ends 15,090,688 */
#define OFF_H1S  3502080    /* fp16, 800K floats (ends 4,302,080); overlays dpart (dead after place) */
#define OFF_H2S  7696384    /* fp16, 1.6M floats (ends 9,296,384); overlays spart (dead after place) */
#define OFF_OUT2 3502080    /* f32 3.2M floats: ends 6,702,080 < 7,696,384 — overlays h1h+dpart
                               (dead after gathm); MUST NOT reach OFF_H2S. */

__device__ __forceinline__ unsigned enc_f(float f) {
    unsigned u = __float_as_uint(f);
    return (u & 0x80000000u) ? ~u : (u | 0x80000000u);
}
__device__ __forceinline__ float dec_f(unsigned u) {
    return (u & 0x80000000u) ? __uint_as_float(u & 0x7fffffffu) : __uint_as_float(~u);
}

// ---------- K0: init fixed sub-segment cursors + zero pool ----------
__global__ void k_init(unsigned* __restrict__ pcur, unsigned* __restrict__ pool) {
    int t = threadIdx.x;
    pcur[t] = (unsigned)t * CAPG;
    if (t < 64) pool[t] = 0u;
}

// ---------- K1: bucket edges into fixed-capacity (p,g) sub-segments ----------
// Block-aggregated reservation: 8 atomics/block onto 256 counters (~20-deep each).
__global__ __launch_bounds__(256) void k_bucket(const int* __restrict__ ei,
                                                unsigned* __restrict__ pcur,
                                                int* __restrict__ dpart,
                                                int* __restrict__ spart) {
    __shared__ unsigned wcnt[4][8];
    __shared__ unsigned woff[4][8];
    int t = threadIdx.x, lane = t & 63, w = t >> 6;
    int g = blockIdx.x & (NGRP - 1);
    int base = blockIdx.x * (256 * BK) + t;
    int dst[BK], src[BK];
    #pragma unroll
    for (int k = 0; k < BK; ++k) {
        dst[k] = ei[NE + base + k * 256];
        src[k] = ei[base + k * 256];
    }
    unsigned long long lt = (lane == 63) ? 0x7fffffffffffffffull
                                         : ((1ull << lane) - 1ull);
    // sweep 1: per-wave per-bin counts (lane b tracks bin b)
    unsigned cnt = 0;
    #pragma unroll
    for (int k = 0; k < BK; ++k) {
        int bin = (unsigned)dst[k] / PSZ;
        #pragma unroll
        for (int b = 0; b < 8; ++b) {
            unsigned long long m = __ballot(bin == b);
            if (lane == b) cnt += (unsigned)__popcll(m);
        }
    }
    if (lane < 8) wcnt[w][lane] = cnt;
    __syncthreads();
    if (t < 8) {
        unsigned c0 = wcnt[0][t], c1 = wcnt[1][t], c2 = wcnt[2][t], c3 = wcnt[3][t];
        unsigned b = atomicAdd(&pcur[t * NGRP + g], c0 + c1 + c2 + c3);
        woff[0][t] = b;
        woff[1][t] = b + c0;
        woff[2][t] = b + c0 + c1;
        woff[3][t] = b + c0 + c1 + c2;
    }
    __syncthreads();
    unsigned run = (lane < 8) ? woff[w][lane] : 0u;
    // sweep 2: place
    #pragma unroll
    for (int k = 0; k < BK; ++k) {
        int bin = (unsigned)dst[k] / PSZ;
        unsigned long long mym = 0;
        unsigned myrun = 0;
        #pragma unroll
        for (int b = 0; b < 8; ++b) {
            unsigned long long m = __ballot(bin == b);
            unsigned r = __shfl(run, b);
            if (bin == b) { mym = m; myrun = r; }
            if (lane == b) run += (unsigned)__popcll(m);
        }
        unsigned pos = myrun + (unsigned)__popcll(mym & lt);
        dpart[pos] = dst[k];
        spart[pos] = src[k];
    }
}

// ---------- K2: per-(p,g) LDS histograms -> hist[p][g][i] ----------
// p = blockIdx&7 keeps partition<->XCD L2 locality.
__global__ __launch_bounds__(256) void k_hist(const unsigned* __restrict__ pcur,
                                              const int* __restrict__ dpart,
                                              unsigned* __restrict__ hist) {
    __shared__ unsigned lh[PSZ];
    int p = blockIdx.x & 7;
    int g = blockIdx.x >> 3;               // 0..NGRP-1
    int ci = p * NGRP + g;
    int t = threadIdx.x;
    for (int i = t; i < PSZ; i += 256) lh[i] = 0;
    __syncthreads();
    unsigned s = (unsigned)ci * CAPG;
    unsigned e = pcur[ci];
    int pb = p * PSZ;
    for (unsigned j = s + t; j < e; j += 256)
        atomicAdd(&lh[dpart[j] - pb], 1u);
    __syncthreads();
    unsigned* hrow = hist + (unsigned)ci * PSZ;
    for (int i = t; i < PSZ; i += 256) hrow[i] = lh[i];
}

// ---------- K3: scan chunk counts per bin -> chunk bases (in place) + deg + bsum ----------
__global__ __launch_bounds__(256) void k_colscan(unsigned* __restrict__ hist,
                                                 unsigned* __restrict__ deg,
                                                 unsigned* __restrict__ bsum) {
    __shared__ unsigned W[4];
    int t = threadIdx.x;
    int gid = blockIdx.x * 256 + t;
    unsigned run = 0;
    if (gid < NN) {
        int p = gid / PSZ, i = gid % PSZ;
        #pragma unroll
        for (int c = 0; c < NGRP; ++c) {
            unsigned idx = (unsigned)(p * NGRP + c) * PSZ + i;
            unsigned v = hist[idx];
            hist[idx] = run;
            run += v;
        }
        deg[gid] = run;
    }
    // fused block sum for global prefix
    unsigned d = (gid < NN) ? run : 0u;
    #pragma unroll
    for (int off = 1; off < 64; off <<= 1) d += __shfl_xor(d, off);
    if ((t & 63) == 0) W[t >> 6] = d;
    __syncthreads();
    if (t == 0) bsum[blockIdx.x] = W[0] + W[1] + W[2] + W[3];
}

// ---------- K4: exclusive scan of block sums (1 block) ----------
__global__ __launch_bounds__(512) void k_bscan(unsigned* __restrict__ bsum) {
    __shared__ unsigned S[512];
    int t = threadIdx.x;
    unsigned v = (t < NBLK) ? bsum[t] : 0u;
    S[t] = v;
    __syncthreads();
    for (int off = 1; off < 512; off <<= 1) {
        unsigned u = (t >= off) ? S[t - off] : 0u;
        __syncthreads();
        S[t] += u;
        __syncthreads();
    }
    if (t < NBLK) bsum[t] = S[t] - v;   // exclusive prefix
}

// ---------- K5: per-block scan -> cursor[i] = rowptr[i+1] (inclusive), dinv ----------
__global__ void k_cscan(const unsigned* __restrict__ deg, const unsigned* __restrict__ bsum,
                        unsigned* __restrict__ cursor, float* __restrict__ dinv) {
    __shared__ unsigned S[256];
    int t = threadIdx.x;
    int i = blockIdx.x * 256 + t;
    unsigned d = (i < NN) ? deg[i] : 0u;
    S[t] = d;
    __syncthreads();
    for (int off = 1; off < 256; off <<= 1) {
        unsigned u = (t >= off) ? S[t - off] : 0u;
        __syncthreads();
        S[t] += u;
        __syncthreads();
    }
    if (i < NN) {
        cursor[i] = bsum[blockIdx.x] + S[t];       // inclusive = rowptr[i+1]
        dinv[i] = rsqrtf((float)(d + 1u));
    }
}

// ---------- K6: place edges via LDS cursors (no global atomics) ----------
__global__ __launch_bounds__(256) void k_place(const unsigned* __restrict__ pcur,
                                               const int* __restrict__ dpart,
                                               const int* __restrict__ spart,
                                               const unsigned* __restrict__ hist,
                                               const unsigned* __restrict__ cursor,
                                               int* __restrict__ ecol) {
    __shared__ unsigned lcur[PSZ];
    int p = blockIdx.x & 7;
    int g = blockIdx.x >> 3;
    int ci = p * NGRP + g;
    int t = threadIdx.x;
    int pb = p * PSZ;
    const unsigned* hrow = hist + (unsigned)ci * PSZ;
    for (int i = t; i < PSZ; i += 256) {
        int gi = pb + i;
        unsigned rowstart = gi ? cursor[gi - 1] : 0u;
        lcur[i] = rowstart + hrow[i];
    }
    __syncthreads();
    unsigned s = (unsigned)ci * CAPG;
    unsigned e = pcur[ci];
    for (unsigned j = s + t; j < e; j += 256) {
        int dst = dpart[j];
        int src = spart[j];
        unsigned pos = atomicAdd(&lcur[dst - pb], 1u);
        ecol[pos] = src;
    }
}

// ---------- K7: h1h = fp16((X @ W1) * dinv[row]) — thread-per-row, scalar W ----------
// W1 accesses are thread-uniform -> compiler emits s_load (SGPR broadcast); no LDS.
__device__ __forceinline__ void fma16g(float xk, const float* __restrict__ w,
                                       float* __restrict__ acc) {
    #pragma unroll
    for (int o = 0; o < 16; ++o) acc[o] += xk * w[o];
}

__global__ __launch_bounds__(64) void k_gemm1(const float* __restrict__ X,
                                              const float* __restrict__ W1,
                                              const float* __restrict__ dinv,
                                              __half2* __restrict__ h1h) {
    int row = blockIdx.x * 64 + threadIdx.x;
    if (row >= NN) return;
    const float4* xr = (const float4*)(X + (size_t)row * FIN);
    float acc[16] = {};
    #pragma unroll 1
    for (int c = 0; c < 8; ++c) {
        float4 xq[8];
        #pragma unroll
        for (int i = 0; i < 8; ++i) xq[i] = xr[c * 8 + i];
        const float* xf = (const float*)xq;
        #pragma unroll
        for (int kk = 0; kk < 32; ++kk)
            fma16g(xf[kk], W1 + (c * 32 + kk) * 16, acc);
    }
    float dv = dinv[row];
    union { __half2 h[8]; uint4 u[2]; } pk;
    #pragma unroll
    for (int o = 0; o < 8; ++o)
        pk.h[o] = __floats2half2_rn(acc[2 * o] * dv, acc[2 * o + 1] * dv);
    uint4* dst = (uint4*)(h1h + (size_t)row * 8);
    dst[0] = pk.u[0];
    dst[1] = pk.u[1];
}

// ---------- K8: fused gather-1 + gemm2 — node per 8-lane group (8 nodes/wave) ----------
__global__ __launch_bounds__(256) void k_gathm(const unsigned* __restrict__ cursor,
                                               const int* __restrict__ ecol,
                                               const float* __restrict__ dinv,
                                               const float* __restrict__ b1,
                                               const float* __restrict__ W2,
                                               const __half2* __restrict__ h1h,
                                               __half2* __restrict__ h2h) {
    __shared__ float Ws[512];   // W2 [16][32]
    __shared__ float B1[16];
    int tid = threadIdx.x;
    Ws[tid] = W2[tid];
    Ws[tid + 256] = W2[tid + 256];
    if (tid < 16) B1[tid] = b1[tid];
    __syncthreads();
    int lane = tid & 63;
    int grp = lane >> 3, f2 = lane & 7;
    int node = blockIdx.x * 32 + (tid >> 6) * 8 + grp;
    unsigned s = node ? cursor[node - 1] : 0u;
    unsigned e = cursor[node];
    float2 acc = __half22float2(h1h[(size_t)node * 8 + f2]);   // self term
    for (unsigned j = s; j < e; j += 4) {
        bool v1 = j + 1 < e, v2 = j + 2 < e, v3 = j + 3 < e;
        int c0 = ecol[j];
        int c1 = v1 ? ecol[j + 1] : c0;
        int c2 = v2 ? ecol[j + 2] : c0;
        int c3 = v3 ? ecol[j + 3] : c0;
        float2 a0 = __half22float2(h1h[(size_t)c0 * 8 + f2]);
        float2 a1 = __half22float2(h1h[(size_t)c1 * 8 + f2]);
        float2 a2 = __half22float2(h1h[(size_t)c2 * 8 + f2]);
        float2 a3 = __half22float2(h1h[(size_t)c3 * 8 + f2]);
        float m1 = v1 ? 1.f : 0.f, m2 = v2 ? 1.f : 0.f, m3 = v3 ? 1.f : 0.f;
        acc.x += a0.x + m1 * a1.x + m2 * a2.x + m3 * a3.x;
        acc.y += a0.y + m1 * a1.y + m2 * a2.y + m3 * a3.y;
    }
    float dv = dinv[node];
    float r0 = fmaxf(acc.x * dv + B1[2 * f2], 0.f);
    float r1 = fmaxf(acc.y * dv + B1[2 * f2 + 1], 0.f);
    int gb = lane & 56;
    float rv[16];
    #pragma unroll
    for (int q = 0; q < 8; ++q) {
        rv[2 * q]     = __shfl(r0, gb + q);
        rv[2 * q + 1] = __shfl(r1, gb + q);
    }
    float o0x = 0.f, o0y = 0.f, o1x = 0.f, o1y = 0.f;
    #pragma unroll
    for (int q = 0; q < 16; ++q) {
        float r = rv[q];
        o0x += r * Ws[q * 32 + 2 * f2];
        o0y += r * Ws[q * 32 + 2 * f2 + 1];
        o1x += r * Ws[q * 32 + 2 * f2 + 16];
        o1y += r * Ws[q * 32 + 2 * f2 + 17];
    }
    h2h[(size_t)node * 16 + f2]     = __floats2half2_rn(o0x * dv, o0y * dv);
    h2h[(size_t)node * 16 + f2 + 8] = __floats2half2_rn(o1x * dv, o1y * dv);
}

// ---------- K9: gather layer 2 — node per 16-lane group (4 nodes/wave) ----------
__global__ __launch_bounds__(256) void k_gath2(const unsigned* __restrict__ cursor,
                                               const int* __restrict__ ecol,
                                               const float* __restrict__ dinv,
                                               const float* __restrict__ b2,
                                               const __half2* __restrict__ h2h,
                                               float* __restrict__ out2) {
    int tid = threadIdx.x;
    int lane = tid & 63;
    int grp = lane >> 4, f2 = lane & 15;
    int node = blockIdx.x * 16 + (tid >> 6) * 4 + grp;
    unsigned s = node ? cursor[node - 1] : 0u;
    unsigned e = cursor[node];
    float2 acc = __half22float2(h2h[(size_t)node * 16 + f2]);  // self term
    for (unsigned j = s; j < e; j += 4) {
        bool v1 = j + 1 < e, v2 = j + 2 < e, v3 = j + 3 < e;
        int c0 = ecol[j];
        int c1 = v1 ? ecol[j + 1] : c0;
        int c2 = v2 ? ecol[j + 2] : c0;
        int c3 = v3 ? ecol[j + 3] : c0;
        float2 a0 = __half22float2(h2h[(size_t)c0 * 16 + f2]);
        float2 a1 = __half22float2(h2h[(size_t)c1 * 16 + f2]);
        float2 a2 = __half22float2(h2h[(size_t)c2 * 16 + f2]);
        float2 a3 = __half22float2(h2h[(size_t)c3 * 16 + f2]);
        float m1 = v1 ? 1.f : 0.f, m2 = v2 ? 1.f : 0.f, m3 = v3 ? 1.f : 0.f;
        acc.x += a0.x + m1 * a1.x + m2 * a2.x + m3 * a3.x;
        acc.y += a0.y + m1 * a1.y + m2 * a2.y + m3 * a3.y;
    }
    float dv = dinv[node];
    float2 b = ((const float2*)b2)[f2];
    ((float2*)(out2 + (size_t)node * F2))[f2] =
        make_float2(acc.x * dv + b.x, acc.y * dv + b.y);
}

// ---------- K10: conv1d(32->64, k=3, pad 1) + global max ----------
#define NPB 256
__global__ __launch_bounds__(256) void k_conv(const float* __restrict__ h2f,
                                              const float* __restrict__ cw,
                                              unsigned* __restrict__ pool) {
    __shared__ float Hs[NPB + 2][33];
    __shared__ float Wt[3 * 32 * 64];
    __shared__ float4 Ms[4][16];
    int tid = threadIdx.x;
    int base = blockIdx.x * NPB;
    for (int idx = tid; idx < 6144; idx += 256) {
        int o = idx / 96, r = idx % 96, ci = r / 3, k = r % 3;
        Wt[(k * 32 + ci) * 64 + o] = cw[idx];
    }
    for (int idx = tid; idx < (NPB + 2) * 8; idx += 256) {
        int j = idx >> 3, c4 = (idx & 7) << 2;
        int g = base + j - 1;
        float4 v = make_float4(0.f, 0.f, 0.f, 0.f);
        if (g >= 0 && g < NN) v = *(const float4*)(h2f + (size_t)g * F2 + c4);
        Hs[j][c4 + 0] = v.x;
        Hs[j][c4 + 1] = v.y;
        Hs[j][c4 + 2] = v.z;
        Hs[j][c4 + 3] = v.w;
    }
    __syncthreads();

    int o4 = (tid & 15) * 4;
    int ng = tid >> 4;
    float4 acc[16] = {};
    for (int ci = 0; ci < 32; ++ci) {
        float h[18];
        #pragma unroll
        for (int j = 0; j < 18; ++j) h[j] = Hs[ng * 16 + j][ci];
        #pragma unroll
        for (int k = 0; k < 3; ++k) {
            float4 w = *(const float4*)&Wt[(k * 32 + ci) * 64 + o4];
            #pragma unroll
            for (int i = 0; i < 16; ++i) {
                float hv = h[i + k];
                acc[i].x += hv * w.x;
                acc[i].y += hv * w.y;
                acc[i].z += hv * w.z;
                acc[i].w += hv * w.w;
            }
        }
    }
    const float NI = -3.0e38f;
    float4 m4 = make_float4(NI, NI, NI, NI);
    #pragma unroll
    for (int i = 0; i < 16; ++i) {
        if (base + ng * 16 + i < NN) {
            m4.x = fmaxf(m4.x, acc[i].x);
            m4.y = fmaxf(m4.y, acc[i].y);
            m4.z = fmaxf(m4.z, acc[i].z);
            m4.w = fmaxf(m4.w, acc[i].w);
        }
    }
    #pragma unroll
    for (int off = 16; off <= 32; off <<= 1) {
        m4.x = fmaxf(m4.x, __shfl_xor(m4.x, off));
        m4.y = fmaxf(m4.y, __shfl_xor(m4.y, off));
        m4.z = fmaxf(m4.z, __shfl_xor(m4.z, off));
        m4.w = fmaxf(m4.w, __shfl_xor(m4.w, off));
    }
    int lane = tid & 63, wv = tid >> 6;
    if (lane < 16) Ms[wv][lane] = m4;
    __syncthreads();
    if (tid < 16) {
        float4 a = Ms[0][tid], b = Ms[1][tid], c = Ms[2][tid], d = Ms[3][tid];
        a.x = fmaxf(fmaxf(a.x, b.x), fmaxf(c.x, d.x));
        a.y = fmaxf(fmaxf(a.y, b.y), fmaxf(c.y, d.y));
        a.z = fmaxf(fmaxf(a.z, b.z), fmaxf(c.z, d.z));
        a.w = fmaxf(fmaxf(a.w, b.w), fmaxf(c.w, d.w));
        int o = tid * 4;
        atomicMax(&pool[o + 0], enc_f(a.x));
        atomicMax(&pool[o + 1], enc_f(a.y));
        atomicMax(&pool[o + 2], enc_f(a.z));
        atomicMax(&pool[o + 3], enc_f(a.w));
    }
}

// ---------- K11: out = (pooled + conv_b) @ fc_w^T + fc_b ----------
__global__ void k_fc(const unsigned* __restrict__ pool, const float* __restrict__ cb,
                     const float* __restrict__ fw, const float* __restrict__ fb,
                     float* __restrict__ out) {
    __shared__ float P[64];
    int tid = threadIdx.x;
    if (tid < 64) P[tid] = dec_f(pool[tid]) + cb[tid];
    __syncthreads();
    int j = blockIdx.x * 256 + tid;
    if (j >= NC) return;
    float s = fb[j];
    const float4* wr = (const float4*)(fw + (size_t)j * CO);
    #pragma unroll
    for (int c = 0; c < 16; ++c) {
        float4 w = wr[c];
        s += P[c * 4 + 0] * w.x + P[c * 4 + 1] * w.y +
             P[c * 4 + 2] * w.z + P[c * 4 + 3] * w.w;
    }
    out[j] = s;
}

extern "C" void kernel_launch(void* const* d_in, const int* in_sizes, int n_in,
                              void* d_out, int out_size, void* d_ws, size_t ws_size,
                              hipStream_t stream) {
    const float* x  = (const float*)d_in[0];
    const int*   ei = (const int*)d_in[1];
    const float* W1 = (const float*)d_in[2];
    const float* b1 = (const float*)d_in[3];
    const float* W2 = (const float*)d_in[4];
    const float* b2 = (const float*)d_in[5];
    const float* cw = (const float*)d_in[6];
    const float* cb = (const float*)d_in[7];
    const float* fw = (const float*)d_in[8];
    const float* fb = (const float*)d_in[9];

    float* ws = (float*)d_ws;
    float*    dinv   = ws + OFF_DINV;
    unsigned* cursor = (unsigned*)(ws + OFF_CUR);
    unsigned* deg    = (unsigned*)(ws + OFF_DEG);
    int*      ecol   = (int*)(ws + OFF_ECOL);
    unsigned* pcur   = (unsigned*)(ws + OFF_MISC);
    unsigned* pool   = pcur + 256;
    unsigned* bsum   = pcur + 320;
    int*      dpart  = (int*)(ws + OFF_DPART);
    int*      spart  = (int*)(ws + OFF_SPART);
    unsigned* hist   = (unsigned*)(ws + OFF_HIST);
    __half2*  h1h    = (__half2*)(ws + OFF_H1S);
    __half2*  h2h    = (__half2*)(ws + OFF_H2S);
    float*    out2   = ws + OFF_OUT2;

    k_init   <<<1, 256, 0, stream>>>(pcur, pool);
    k_bucket <<<NE / (256 * BK), 256, 0, stream>>>(ei, pcur, dpart, spart);   // 625
    k_hist   <<<NPART * NGRP, 256, 0, stream>>>(pcur, dpart, hist);           // 256
    k_colscan<<<NBLK, 256, 0, stream>>>(hist, deg, bsum);
    k_bscan  <<<1, 512, 0, stream>>>(bsum);
    k_cscan  <<<NBLK, 256, 0, stream>>>(deg, bsum, cursor, dinv);
    k_place  <<<NPART * NGRP, 256, 0, stream>>>(pcur, dpart, spart, hist, cursor, ecol);
    k_gemm1  <<<GBLK, 64, 0, stream>>>(x, W1, dinv, h1h);                     // 1563
    k_gathm  <<<NN / 32, 256, 0, stream>>>(cursor, ecol, dinv, b1, W2, h1h, h2h);   // 3125
    k_gath2  <<<NN / 16, 256, 0, stream>>>(cursor, ecol, dinv, b2, h2h, out2);      // 6250
    k_conv   <<<(NN + NPB - 1) / NPB, 256, 0, stream>>>(out2, cw, pool);
    k_fc     <<<4, 256, 0, stream>>>(pool, cb, fw, fb, (float*)d_out);
}

// Round 16
// 245.155 us; speedup vs baseline: 1.8837x; 1.1201x over previous
//
#include <hip/hip_runtime.h>
#include <hip/hip_bf16.h>
#include <hip/hip_fp16.h>

#define NN 100000
#define NE 3200000
#define FIN 256
#define F1 16
#define F2 32
#define CO 64
#define NC 1000
#define NBLK 391   /* ceil(NN/256) */
#define GBLK 1563  /* ceil(NN/64) gemm1 grid (64-thread blocks, 1 row/thread) */
#define NPART 8
#define NGRP 32    /* sub-segments (groups) per partition */
#define CAPG 16384 /* fixed capacity per (partition,group) sub-segment */
#define PSZ 12500  /* NN / NPART */
#define BK 20      /* edges per thread in bucket; 625 blocks * 256 * 20 = NE */
#define SRCMASK 0x1FFFFu   /* low 17 bits = src; high bits = dst_local */

// workspace layout (float offsets) — total 10,896,384 floats = 43.6 MB
#define OFF_DINV 0
#define OFF_CUR  100352
#define OFF_DEG  200704
#define OFF_ECOL 301056
#define OFF_MISC 3501056    /* pcur[256]@0, pool[64]@256, bsum[391]@320 (ends 711 < 1024) */
#define OFF_EPART 3502080   /* u32[256*16384] = 4,194,304 -> ends 7,696,384 */
#define OFF_HIST  7696384   /* u32[8*32*12500] = 3.2M -> ends 10,896,384 */
#define OFF_H1S   3502080   /* fp16, 800K floats (ends 4,302,080); overlays epart (dead after place) */
#define OFF_H2S   4302080   /* fp16, 1.6M floats (ends 5,902,080); overlays epart (dead after place) */
#define OFF_OUT2  5902080   /* f32 3.2M floats (ends 9,102,080); overlays epart tail + hist (both dead
                               after place). MUST NOT touch h2h (<5,902,080) or ecol (<3,501,056). */

__device__ __forceinline__ unsigned enc_f(float f) {
    unsigned u = __float_as_uint(f);
    return (u & 0x80000000u) ? ~u : (u | 0x80000000u);
}
__device__ __forceinline__ float dec_f(unsigned u) {
    return (u & 0x80000000u) ? __uint_as_float(u & 0x7fffffffu) : __uint_as_float(~u);
}

// ---------- K0: init fixed sub-segment cursors + zero pool ----------
__global__ void k_init(unsigned* __restrict__ pcur, unsigned* __restrict__ pool) {
    int t = threadIdx.x;
    pcur[t] = (unsigned)t * CAPG;
    if (t < 64) pool[t] = 0u;
}

// ---------- K1: bucket edges into fixed-capacity (p,g) sub-segments, packed u32 ----------
__global__ __launch_bounds__(256) void k_bucket(const int* __restrict__ ei,
                                                unsigned* __restrict__ pcur,
                                                unsigned* __restrict__ epart) {
    __shared__ unsigned wcnt[4][8];
    __shared__ unsigned woff[4][8];
    int t = threadIdx.x, lane = t & 63, w = t >> 6;
    int g = blockIdx.x & (NGRP - 1);
    int base = blockIdx.x * (256 * BK) + t;
    int dst[BK], src[BK];
    #pragma unroll
    for (int k = 0; k < BK; ++k) {
        dst[k] = ei[NE + base + k * 256];
        src[k] = ei[base + k * 256];
    }
    unsigned long long lt = (lane == 63) ? 0x7fffffffffffffffull
                                         : ((1ull << lane) - 1ull);
    // sweep 1: per-wave per-bin counts (lane b tracks bin b)
    unsigned cnt = 0;
    #pragma unroll
    for (int k = 0; k < BK; ++k) {
        int bin = (unsigned)dst[k] / PSZ;
        #pragma unroll
        for (int b = 0; b < 8; ++b) {
            unsigned long long m = __ballot(bin == b);
            if (lane == b) cnt += (unsigned)__popcll(m);
        }
    }
    if (lane < 8) wcnt[w][lane] = cnt;
    __syncthreads();
    if (t < 8) {
        unsigned c0 = wcnt[0][t], c1 = wcnt[1][t], c2 = wcnt[2][t], c3 = wcnt[3][t];
        unsigned b = atomicAdd(&pcur[t * NGRP + g], c0 + c1 + c2 + c3);
        woff[0][t] = b;
        woff[1][t] = b + c0;
        woff[2][t] = b + c0 + c1;
        woff[3][t] = b + c0 + c1 + c2;
    }
    __syncthreads();
    unsigned run = (lane < 8) ? woff[w][lane] : 0u;
    // sweep 2: place packed (dst_local<<17 | src)
    #pragma unroll
    for (int k = 0; k < BK; ++k) {
        int bin = (unsigned)dst[k] / PSZ;
        unsigned long long mym = 0;
        unsigned myrun = 0;
        #pragma unroll
        for (int b = 0; b < 8; ++b) {
            unsigned long long m = __ballot(bin == b);
            unsigned r = __shfl(run, b);
            if (bin == b) { mym = m; myrun = r; }
            if (lane == b) run += (unsigned)__popcll(m);
        }
        unsigned pos = myrun + (unsigned)__popcll(mym & lt);
        epart[pos] = ((unsigned)(dst[k] - bin * PSZ) << 17) | (unsigned)src[k];
    }
}

// ---------- K2: per-(p,g) LDS histograms -> hist[p][g][i] ----------
__global__ __launch_bounds__(256) void k_hist(const unsigned* __restrict__ pcur,
                                              const unsigned* __restrict__ epart,
                                              unsigned* __restrict__ hist) {
    __shared__ unsigned lh[PSZ];
    int p = blockIdx.x & 7;
    int g = blockIdx.x >> 3;               // 0..NGRP-1
    int ci = p * NGRP + g;
    int t = threadIdx.x;
    for (int i = t; i < PSZ; i += 256) lh[i] = 0;
    __syncthreads();
    unsigned s = (unsigned)ci * CAPG;
    unsigned e = pcur[ci];
    for (unsigned j = s + t; j < e; j += 256)
        atomicAdd(&lh[epart[j] >> 17], 1u);
    __syncthreads();
    unsigned* hrow = hist + (unsigned)ci * PSZ;
    for (int i = t; i < PSZ; i += 256) hrow[i] = lh[i];
}

// ---------- K3: scan chunk counts per bin -> chunk bases (in place) + deg + bsum ----------
__global__ __launch_bounds__(256) void k_colscan(unsigned* __restrict__ hist,
                                                 unsigned* __restrict__ deg,
                                                 unsigned* __restrict__ bsum) {
    __shared__ unsigned W[4];
    int t = threadIdx.x;
    int gid = blockIdx.x * 256 + t;
    unsigned run = 0;
    if (gid < NN) {
        int p = gid / PSZ, i = gid % PSZ;
        #pragma unroll
        for (int c = 0; c < NGRP; ++c) {
            unsigned idx = (unsigned)(p * NGRP + c) * PSZ + i;
            unsigned v = hist[idx];
            hist[idx] = run;
            run += v;
        }
        deg[gid] = run;
    }
    unsigned d = (gid < NN) ? run : 0u;
    #pragma unroll
    for (int off = 1; off < 64; off <<= 1) d += __shfl_xor(d, off);
    if ((t & 63) == 0) W[t >> 6] = d;
    __syncthreads();
    if (t == 0) bsum[blockIdx.x] = W[0] + W[1] + W[2] + W[3];
}

// ---------- K4: exclusive scan of block sums (1 block) ----------
__global__ __launch_bounds__(512) void k_bscan(unsigned* __restrict__ bsum) {
    __shared__ unsigned S[512];
    int t = threadIdx.x;
    unsigned v = (t < NBLK) ? bsum[t] : 0u;
    S[t] = v;
    __syncthreads();
    for (int off = 1; off < 512; off <<= 1) {
        unsigned u = (t >= off) ? S[t - off] : 0u;
        __syncthreads();
        S[t] += u;
        __syncthreads();
    }
    if (t < NBLK) bsum[t] = S[t] - v;   // exclusive prefix
}

// ---------- K5: per-block scan -> cursor[i] = rowptr[i+1] (inclusive), dinv ----------
__global__ void k_cscan(const unsigned* __restrict__ deg, const unsigned* __restrict__ bsum,
                        unsigned* __restrict__ cursor, float* __restrict__ dinv) {
    __shared__ unsigned S[256];
    int t = threadIdx.x;
    int i = blockIdx.x * 256 + t;
    unsigned d = (i < NN) ? deg[i] : 0u;
    S[t] = d;
    __syncthreads();
    for (int off = 1; off < 256; off <<= 1) {
        unsigned u = (t >= off) ? S[t - off] : 0u;
        __syncthreads();
        S[t] += u;
        __syncthreads();
    }
    if (i < NN) {
        cursor[i] = bsum[blockIdx.x] + S[t];       // inclusive = rowptr[i+1]
        dinv[i] = rsqrtf((float)(d + 1u));
    }
}

// ---------- K6: place edges via LDS cursors (no global atomics) ----------
__global__ __launch_bounds__(256) void k_place(const unsigned* __restrict__ pcur,
                                               const unsigned* __restrict__ epart,
                                               const unsigned* __restrict__ hist,
                                               const unsigned* __restrict__ cursor,
                                               int* __restrict__ ecol) {
    __shared__ unsigned lcur[PSZ];
    int p = blockIdx.x & 7;
    int g = blockIdx.x >> 3;
    int ci = p * NGRP + g;
    int t = threadIdx.x;
    int pb = p * PSZ;
    const unsigned* hrow = hist + (unsigned)ci * PSZ;
    for (int i = t; i < PSZ; i += 256) {
        int gi = pb + i;
        unsigned rowstart = gi ? cursor[gi - 1] : 0u;
        lcur[i] = rowstart + hrow[i];
    }
    __syncthreads();
    unsigned s = (unsigned)ci * CAPG;
    unsigned e = pcur[ci];
    for (unsigned j = s + t; j < e; j += 256) {
        unsigned v = epart[j];
        unsigned pos = atomicAdd(&lcur[v >> 17], 1u);
        ecol[pos] = (int)(v & SRCMASK);
    }
}

// ---------- K7: h1h = fp16((X @ W1) * dinv[row]) — thread-per-row, scalar W ----------
__device__ __forceinline__ void fma16g(float xk, const float* __restrict__ w,
                                       float* __restrict__ acc) {
    #pragma unroll
    for (int o = 0; o < 16; ++o) acc[o] += xk * w[o];
}

__global__ __launch_bounds__(64) void k_gemm1(const float* __restrict__ X,
                                              const float* __restrict__ W1,
                                              const float* __restrict__ dinv,
                                              __half2* __restrict__ h1h) {
    int row = blockIdx.x * 64 + threadIdx.x;
    if (row >= NN) return;
    const float4* xr = (const float4*)(X + (size_t)row * FIN);
    float acc[16] = {};
    #pragma unroll 1
    for (int c = 0; c < 8; ++c) {
        float4 xq[8];
        #pragma unroll
        for (int i = 0; i < 8; ++i) xq[i] = xr[c * 8 + i];
        const float* xf = (const float*)xq;
        #pragma unroll
        for (int kk = 0; kk < 32; ++kk)
            fma16g(xf[kk], W1 + (c * 32 + kk) * 16, acc);
    }
    float dv = dinv[row];
    union { __half2 h[8]; uint4 u[2]; } pk;
    #pragma unroll
    for (int o = 0; o < 8; ++o)
        pk.h[o] = __floats2half2_rn(acc[2 * o] * dv, acc[2 * o + 1] * dv);
    uint4* dst = (uint4*)(h1h + (size_t)row * 8);
    dst[0] = pk.u[0];
    dst[1] = pk.u[1];
}

// ---------- K8: fused gather-1 + gemm2 — node per 8-lane group, masked-8 unroll ----------
__global__ __launch_bounds__(256) void k_gathm(const unsigned* __restrict__ cursor,
                                               const int* __restrict__ ecol,
                                               const float* __restrict__ dinv,
                                               const float* __restrict__ b1,
                                               const float* __restrict__ W2,
                                               const __half2* __restrict__ h1h,
                                               __half2* __restrict__ h2h) {
    __shared__ float Ws[512];   // W2 [16][32]
    __shared__ float B1[16];
    int tid = threadIdx.x;
    Ws[tid] = W2[tid];
    Ws[tid + 256] = W2[tid + 256];
    if (tid < 16) B1[tid] = b1[tid];
    __syncthreads();
    int lane = tid & 63;
    int grp = lane >> 3, f2 = lane & 7;
    int node = blockIdx.x * 32 + (tid >> 6) * 8 + grp;
    unsigned s = node ? cursor[node - 1] : 0u;
    unsigned e = cursor[node];
    float2 acc = __half22float2(h1h[(size_t)node * 8 + f2]);   // self term
    for (unsigned j = s; j < e; j += 8) {
        int cc[8]; float msk[8];
        #pragma unroll
        for (int q = 0; q < 8; ++q) {
            unsigned jj = j + q;
            bool v = jj < e;
            cc[q] = ecol[v ? jj : j];
            msk[q] = v ? 1.f : 0.f;
        }
        float2 a[8];
        #pragma unroll
        for (int q = 0; q < 8; ++q)
            a[q] = __half22float2(h1h[(size_t)cc[q] * 8 + f2]);
        #pragma unroll
        for (int q = 0; q < 8; ++q) {
            acc.x += msk[q] * a[q].x;
            acc.y += msk[q] * a[q].y;
        }
    }
    float dv = dinv[node];
    float r0 = fmaxf(acc.x * dv + B1[2 * f2], 0.f);
    float r1 = fmaxf(acc.y * dv + B1[2 * f2 + 1], 0.f);
    int gb = lane & 56;
    float rv[16];
    #pragma unroll
    for (int q = 0; q < 8; ++q) {
        rv[2 * q]     = __shfl(r0, gb + q);
        rv[2 * q + 1] = __shfl(r1, gb + q);
    }
    float o0x = 0.f, o0y = 0.f, o1x = 0.f, o1y = 0.f;
    #pragma unroll
    for (int q = 0; q < 16; ++q) {
        float r = rv[q];
        o0x += r * Ws[q * 32 + 2 * f2];
        o0y += r * Ws[q * 32 + 2 * f2 + 1];
        o1x += r * Ws[q * 32 + 2 * f2 + 16];
        o1y += r * Ws[q * 32 + 2 * f2 + 17];
    }
    h2h[(size_t)node * 16 + f2]     = __floats2half2_rn(o0x * dv, o0y * dv);
    h2h[(size_t)node * 16 + f2 + 8] = __floats2half2_rn(o1x * dv, o1y * dv);
}

// ---------- K9: gather layer 2 — node per 16-lane group, masked-8 unroll ----------
__global__ __launch_bounds__(256) void k_gath2(const unsigned* __restrict__ cursor,
                                               const int* __restrict__ ecol,
                                               const float* __restrict__ dinv,
                                               const float* __restrict__ b2,
                                               const __half2* __restrict__ h2h,
                                               float* __restrict__ out2) {
    int tid = threadIdx.x;
    int lane = tid & 63;
    int grp = lane >> 4, f2 = lane & 15;
    int node = blockIdx.x * 16 + (tid >> 6) * 4 + grp;
    unsigned s = node ? cursor[node - 1] : 0u;
    unsigned e = cursor[node];
    float2 acc = __half22float2(h2h[(size_t)node * 16 + f2]);  // self term
    for (unsigned j = s; j < e; j += 8) {
        int cc[8]; float msk[8];
        #pragma unroll
        for (int q = 0; q < 8; ++q) {
            unsigned jj = j + q;
            bool v = jj < e;
            cc[q] = ecol[v ? jj : j];
            msk[q] = v ? 1.f : 0.f;
        }
        float2 a[8];
        #pragma unroll
        for (int q = 0; q < 8; ++q)
            a[q] = __half22float2(h2h[(size_t)cc[q] * 16 + f2]);
        #pragma unroll
        for (int q = 0; q < 8; ++q) {
            acc.x += msk[q] * a[q].x;
            acc.y += msk[q] * a[q].y;
        }
    }
    float dv = dinv[node];
    float2 b = ((const float2*)b2)[f2];
    ((float2*)(out2 + (size_t)node * F2))[f2] =
        make_float2(acc.x * dv + b.x, acc.y * dv + b.y);
}

// ---------- K10: conv1d(32->64, k=3, pad 1) + global max ----------
#define NPB 256
__global__ __launch_bounds__(256) void k_conv(const float* __restrict__ h2f,
                                              const float* __restrict__ cw,
                                              unsigned* __restrict__ pool) {
    __shared__ float Hs[NPB + 2][33];
    __shared__ float Wt[3 * 32 * 64];
    __shared__ float4 Ms[4][16];
    int tid = threadIdx.x;
    int base = blockIdx.x * NPB;
    for (int idx = tid; idx < 6144; idx += 256) {
        int o = idx / 96, r = idx % 96, ci = r / 3, k = r % 3;
        Wt[(k * 32 + ci) * 64 + o] = cw[idx];
    }
    for (int idx = tid; idx < (NPB + 2) * 8; idx += 256) {
        int j = idx >> 3, c4 = (idx & 7) << 2;
        int g = base + j - 1;
        float4 v = make_float4(0.f, 0.f, 0.f, 0.f);
        if (g >= 0 && g < NN) v = *(const float4*)(h2f + (size_t)g * F2 + c4);
        Hs[j][c4 + 0] = v.x;
        Hs[j][c4 + 1] = v.y;
        Hs[j][c4 + 2] = v.z;
        Hs[j][c4 + 3] = v.w;
    }
    __syncthreads();

    int o4 = (tid & 15) * 4;
    int ng = tid >> 4;
    float4 acc[16] = {};
    for (int ci = 0; ci < 32; ++ci) {
        float h[18];
        #pragma unroll
        for (int j = 0; j < 18; ++j) h[j] = Hs[ng * 16 + j][ci];
        #pragma unroll
        for (int k = 0; k < 3; ++k) {
            float4 w = *(const float4*)&Wt[(k * 32 + ci) * 64 + o4];
            #pragma unroll
            for (int i = 0; i < 16; ++i) {
                float hv = h[i + k];
                acc[i].x += hv * w.x;
                acc[i].y += hv * w.y;
                acc[i].z += hv * w.z;
                acc[i].w += hv * w.w;
            }
        }
    }
    const float NI = -3.0e38f;
    float4 m4 = make_float4(NI, NI, NI, NI);
    #pragma unroll
    for (int i = 0; i < 16; ++i) {
        if (base + ng * 16 + i < NN) {
            m4.x = fmaxf(m4.x, acc[i].x);
            m4.y = fmaxf(m4.y, acc[i].y);
            m4.z = fmaxf(m4.z, acc[i].z);
            m4.w = fmaxf(m4.w, acc[i].w);
        }
    }
    #pragma unroll
    for (int off = 16; off <= 32; off <<= 1) {
        m4.x = fmaxf(m4.x, __shfl_xor(m4.x, off));
        m4.y = fmaxf(m4.y, __shfl_xor(m4.y, off));
        m4.z = fmaxf(m4.z, __shfl_xor(m4.z, off));
        m4.w = fmaxf(m4.w, __shfl_xor(m4.w, off));
    }
    int lane = tid & 63, wv = tid >> 6;
    if (lane < 16) Ms[wv][lane] = m4;
    __syncthreads();
    if (tid < 16) {
        float4 a = Ms[0][tid], b = Ms[1][tid], c = Ms[2][tid], d = Ms[3][tid];
        a.x = fmaxf(fmaxf(a.x, b.x), fmaxf(c.x, d.x));
        a.y = fmaxf(fmaxf(a.y, b.y), fmaxf(c.y, d.y));
        a.z = fmaxf(fmaxf(a.z, b.z), fmaxf(c.z, d.z));
        a.w = fmaxf(fmaxf(a.w, b.w), fmaxf(c.w, d.w));
        int o = tid * 4;
        atomicMax(&pool[o + 0], enc_f(a.x));
        atomicMax(&pool[o + 1], enc_f(a.y));
        atomicMax(&pool[o + 2], enc_f(a.z));
        atomicMax(&pool[o + 3], enc_f(a.w));
    }
}

// ---------- K11: out = (pooled + conv_b) @ fc_w^T + fc_b ----------
__global__ void k_fc(const unsigned* __restrict__ pool, const float* __restrict__ cb,
                     const float* __restrict__ fw, const float* __restrict__ fb,
                     float* __restrict__ out) {
    __shared__ float P[64];
    int tid = threadIdx.x;
    if (tid < 64) P[tid] = dec_f(pool[tid]) + cb[tid];
    __syncthreads();
    int j = blockIdx.x * 256 + tid;
    if (j >= NC) return;
    float s = fb[j];
    const float4* wr = (const float4*)(fw + (size_t)j * CO);
    #pragma unroll
    for (int c = 0; c < 16; ++c) {
        float4 w = wr[c];
        s += P[c * 4 + 0] * w.x + P[c * 4 + 1] * w.y +
             P[c * 4 + 2] * w.z + P[c * 4 + 3] * w.w;
    }
    out[j] = s;
}

extern "C" void kernel_launch(void* const* d_in, const int* in_sizes, int n_in,
                              void* d_out, int out_size, void* d_ws, size_t ws_size,
                              hipStream_t stream) {
    const float* x  = (const float*)d_in[0];
    const int*   ei = (const int*)d_in[1];
    const float* W1 = (const float*)d_in[2];
    const float* b1 = (const float*)d_in[3];
    const float* W2 = (const float*)d_in[4];
    const float* b2 = (const float*)d_in[5];
    const float* cw = (const float*)d_in[6];
    const float* cb = (const float*)d_in[7];
    const float* fw = (const float*)d_in[8];
    const float* fb = (const float*)d_in[9];

    float* ws = (float*)d_ws;
    float*    dinv   = ws + OFF_DINV;
    unsigned* cursor = (unsigned*)(ws + OFF_CUR);
    unsigned* deg    = (unsigned*)(ws + OFF_DEG);
    int*      ecol   = (int*)(ws + OFF_ECOL);
    unsigned* pcur   = (unsigned*)(ws + OFF_MISC);
    unsigned* pool   = pcur + 256;
    unsigned* bsum   = pcur + 320;
    unsigned* epart  = (unsigned*)(ws + OFF_EPART);
    unsigned* hist   = (unsigned*)(ws + OFF_HIST);
    __half2*  h1h    = (__half2*)(ws + OFF_H1S);
    __half2*  h2h    = (__half2*)(ws + OFF_H2S);
    float*    out2   = ws + OFF_OUT2;

    k_init   <<<1, 256, 0, stream>>>(pcur, pool);
    k_bucket <<<NE / (256 * BK), 256, 0, stream>>>(ei, pcur, epart);        // 625
    k_hist   <<<NPART * NGRP, 256, 0, stream>>>(pcur, epart, hist);         // 256
    k_colscan<<<NBLK, 256, 0, stream>>>(hist, deg, bsum);
    k_bscan  <<<1, 512, 0, stream>>>(bsum);
    k_cscan  <<<NBLK, 256, 0, stream>>>(deg, bsum, cursor, dinv);
    k_place  <<<NPART * NGRP, 256, 0, stream>>>(pcur, epart, hist, cursor, ecol);
    k_gemm1  <<<GBLK, 64, 0, stream>>>(x, W1, dinv, h1h);                   // 1563
    k_gathm  <<<NN / 32, 256, 0, stream>>>(cursor, ecol, dinv, b1, W2, h1h, h2h);   // 3125
    k_gath2  <<<NN / 16, 256, 0, stream>>>(cursor, ecol, dinv, b2, h2h, out2);      // 6250
    k_conv   <<<(NN + NPB - 1) / NPB, 256, 0, stream>>>(out2, cw, pool);
    k_fc     <<<4, 256, 0, stream>>>(pool, cb, fw, fb, (float*)d_out);
}

// Round 18
// 241.950 us; speedup vs baseline: 1.9086x; 1.0132x over previous
//
#include <hip/hip_runtime.h>
#include <hip/hip_bf16.h>
#include <hip/hip_fp16.h>

#define NN 100000
#define NE 3200000
#define FIN 256
#define F1 16
#define F2 32
#define CO 64
#define NC 1000
#define NBLK 391   /* ceil(NN/256) */
#define GBLK 1563  /* ceil(NN/64) gemm1 grid (64-thread blocks, 1 row/thread) */
#define NPART 8
#define NGRP 32    /* sub-segments (groups) per partition */
#define CAPG 16384 /* fixed capacity per (partition,group) sub-segment */
#define PSZ 12500  /* NN / NPART */
#define BK 20      /* edges per thread in bucket; 625 blocks * 256 * 20 = NE */
#define SRCMASK 0x1FFFFu   /* low 17 bits = src; high bits = dst_local */

// workspace layout (float offsets) — total 10,896,384 floats = 43.6 MB
#define OFF_DINV 0
#define OFF_CUR  100352
#define OFF_DEG  200704
#define OFF_ECOL 301056
#define OFF_MISC 3501056    /* pcur[256]@0, pool[64]@256, bsum[391]@320 (ends 711 < 1024) */
#define OFF_EPART 3502080   /* u32[256*16384] = 4,194,304 -> ends 7,696,384 */
#define OFF_HIST  7696384   /* u32[8*32*12500] = 3.2M -> ends 10,896,384 */
#define OFF_H1S   3502080   /* fp16, 800K floats (ends 4,302,080); overlays epart (dead after place) */
#define OFF_H2S   4302080   /* fp16, 1.6M floats (ends 5,902,080); overlays epart (dead after place) */
#define OFF_OUT2H 5902080   /* fp16, 1.6M floats (ends 7,502,080); overlays epart tail (dead after place) */

__device__ __forceinline__ unsigned enc_f(float f) {
    unsigned u = __float_as_uint(f);
    return (u & 0x80000000u) ? ~u : (u | 0x80000000u);
}
__device__ __forceinline__ float dec_f(unsigned u) {
    return (u & 0x80000000u) ? __uint_as_float(u & 0x7fffffffu) : __uint_as_float(~u);
}

// ---------- K0: init fixed sub-segment cursors + zero pool ----------
__global__ void k_init(unsigned* __restrict__ pcur, unsigned* __restrict__ pool) {
    int t = threadIdx.x;
    pcur[t] = (unsigned)t * CAPG;
    if (t < 64) pool[t] = 0u;
}

// ---------- K1: bucket edges into fixed-capacity (p,g) sub-segments, packed u32 ----------
__global__ __launch_bounds__(256) void k_bucket(const int* __restrict__ ei,
                                                unsigned* __restrict__ pcur,
                                                unsigned* __restrict__ epart) {
    __shared__ unsigned wcnt[4][8];
    __shared__ unsigned woff[4][8];
    int t = threadIdx.x, lane = t & 63, w = t >> 6;
    int g = blockIdx.x & (NGRP - 1);
    int base = blockIdx.x * (256 * BK) + t;
    int dst[BK], src[BK];
    #pragma unroll
    for (int k = 0; k < BK; ++k) {
        dst[k] = ei[NE + base + k * 256];
        src[k] = ei[base + k * 256];
    }
    unsigned long long lt = (lane == 63) ? 0x7fffffffffffffffull
                                         : ((1ull << lane) - 1ull);
    // sweep 1: per-wave per-bin counts (lane b tracks bin b)
    unsigned cnt = 0;
    #pragma unroll
    for (int k = 0; k < BK; ++k) {
        int bin = (unsigned)dst[k] / PSZ;
        #pragma unroll
        for (int b = 0; b < 8; ++b) {
            unsigned long long m = __ballot(bin == b);
            if (lane == b) cnt += (unsigned)__popcll(m);
        }
    }
    if (lane < 8) wcnt[w][lane] = cnt;
    __syncthreads();
    if (t < 8) {
        unsigned c0 = wcnt[0][t], c1 = wcnt[1][t], c2 = wcnt[2][t], c3 = wcnt[3][t];
        unsigned b = atomicAdd(&pcur[t * NGRP + g], c0 + c1 + c2 + c3);
        woff[0][t] = b;
        woff[1][t] = b + c0;
        woff[2][t] = b + c0 + c1;
        woff[3][t] = b + c0 + c1 + c2;
    }
    __syncthreads();
    unsigned run = (lane < 8) ? woff[w][lane] : 0u;
    // sweep 2: place packed (dst_local<<17 | src)
    #pragma unroll
    for (int k = 0; k < BK; ++k) {
        int bin = (unsigned)dst[k] / PSZ;
        unsigned long long mym = 0;
        unsigned myrun = 0;
        #pragma unroll
        for (int b = 0; b < 8; ++b) {
            unsigned long long m = __ballot(bin == b);
            unsigned r = __shfl(run, b);
            if (bin == b) { mym = m; myrun = r; }
            if (lane == b) run += (unsigned)__popcll(m);
        }
        unsigned pos = myrun + (unsigned)__popcll(mym & lt);
        epart[pos] = ((unsigned)(dst[k] - bin * PSZ) << 17) | (unsigned)src[k];
    }
}

// ---------- K2: per-(p,g) LDS histograms -> hist[p][g][i] ----------
__global__ __launch_bounds__(256) void k_hist(const unsigned* __restrict__ pcur,
                                              const unsigned* __restrict__ epart,
                                              unsigned* __restrict__ hist) {
    __shared__ unsigned lh[PSZ];
    int p = blockIdx.x & 7;
    int g = blockIdx.x >> 3;               // 0..NGRP-1
    int ci = p * NGRP + g;
    int t = threadIdx.x;
    for (int i = t; i < PSZ; i += 256) lh[i] = 0;
    __syncthreads();
    unsigned s = (unsigned)ci * CAPG;
    unsigned e = pcur[ci];
    for (unsigned j = s + t; j < e; j += 256)
        atomicAdd(&lh[epart[j] >> 17], 1u);
    __syncthreads();
    unsigned* hrow = hist + (unsigned)ci * PSZ;
    for (int i = t; i < PSZ; i += 256) hrow[i] = lh[i];
}

// ---------- K3: scan chunk counts per bin -> chunk bases (in place) + deg + bsum ----------
__global__ __launch_bounds__(256) void k_colscan(unsigned* __restrict__ hist,
                                                 unsigned* __restrict__ deg,
                                                 unsigned* __restrict__ bsum) {
    __shared__ unsigned W[4];
    int t = threadIdx.x;
    int gid = blockIdx.x * 256 + t;
    unsigned run = 0;
    if (gid < NN) {
        int p = gid / PSZ, i = gid % PSZ;
        #pragma unroll
        for (int c = 0; c < NGRP; ++c) {
            unsigned idx = (unsigned)(p * NGRP + c) * PSZ + i;
            unsigned v = hist[idx];
            hist[idx] = run;
            run += v;
        }
        deg[gid] = run;
    }
    unsigned d = (gid < NN) ? run : 0u;
    #pragma unroll
    for (int off = 1; off < 64; off <<= 1) d += __shfl_xor(d, off);
    if ((t & 63) == 0) W[t >> 6] = d;
    __syncthreads();
    if (t == 0) bsum[blockIdx.x] = W[0] + W[1] + W[2] + W[3];
}

// ---------- K4: exclusive scan of block sums (1 block) ----------
__global__ __launch_bounds__(512) void k_bscan(unsigned* __restrict__ bsum) {
    __shared__ unsigned S[512];
    int t = threadIdx.x;
    unsigned v = (t < NBLK) ? bsum[t] : 0u;
    S[t] = v;
    __syncthreads();
    for (int off = 1; off < 512; off <<= 1) {
        unsigned u = (t >= off) ? S[t - off] : 0u;
        __syncthreads();
        S[t] += u;
        __syncthreads();
    }
    if (t < NBLK) bsum[t] = S[t] - v;   // exclusive prefix
}

// ---------- K5: per-block scan -> cursor[i] = rowptr[i+1] (inclusive), dinv ----------
__global__ void k_cscan(const unsigned* __restrict__ deg, const unsigned* __restrict__ bsum,
                        unsigned* __restrict__ cursor, float* __restrict__ dinv) {
    __shared__ unsigned S[256];
    int t = threadIdx.x;
    int i = blockIdx.x * 256 + t;
    unsigned d = (i < NN) ? deg[i] : 0u;
    S[t] = d;
    __syncthreads();
    for (int off = 1; off < 256; off <<= 1) {
        unsigned u = (t >= off) ? S[t - off] : 0u;
        __syncthreads();
        S[t] += u;
        __syncthreads();
    }
    if (i < NN) {
        cursor[i] = bsum[blockIdx.x] + S[t];       // inclusive = rowptr[i+1]
        dinv[i] = rsqrtf((float)(d + 1u));
    }
}

// ---------- K6: place edges via LDS cursors (no global atomics) ----------
__global__ __launch_bounds__(256) void k_place(const unsigned* __restrict__ pcur,
                                               const unsigned* __restrict__ epart,
                                               const unsigned* __restrict__ hist,
                                               const unsigned* __restrict__ cursor,
                                               int* __restrict__ ecol) {
    __shared__ unsigned lcur[PSZ];
    int p = blockIdx.x & 7;
    int g = blockIdx.x >> 3;
    int ci = p * NGRP + g;
    int t = threadIdx.x;
    int pb = p * PSZ;
    const unsigned* hrow = hist + (unsigned)ci * PSZ;
    for (int i = t; i < PSZ; i += 256) {
        int gi = pb + i;
        unsigned rowstart = gi ? cursor[gi - 1] : 0u;
        lcur[i] = rowstart + hrow[i];
    }
    __syncthreads();
    unsigned s = (unsigned)ci * CAPG;
    unsigned e = pcur[ci];
    for (unsigned j = s + t; j < e; j += 256) {
        unsigned v = epart[j];
        unsigned pos = atomicAdd(&lcur[v >> 17], 1u);
        ecol[pos] = (int)(v & SRCMASK);
    }
}

// ---------- K7: h1h = fp16((X @ W1) * dinv[row]) — thread-per-row, scalar W ----------
__device__ __forceinline__ void fma16g(float xk, const float* __restrict__ w,
                                       float* __restrict__ acc) {
    #pragma unroll
    for (int o = 0; o < 16; ++o) acc[o] += xk * w[o];
}

__global__ __launch_bounds__(64) void k_gemm1(const float* __restrict__ X,
                                              const float* __restrict__ W1,
                                              const float* __restrict__ dinv,
                                              __half2* __restrict__ h1h) {
    int row = blockIdx.x * 64 + threadIdx.x;
    if (row >= NN) return;
    const float4* xr = (const float4*)(X + (size_t)row * FIN);
    float acc[16] = {};
    #pragma unroll 1
    for (int c = 0; c < 8; ++c) {
        float4 xq[8];
        #pragma unroll
        for (int i = 0; i < 8; ++i) xq[i] = xr[c * 8 + i];
        const float* xf = (const float*)xq;
        #pragma unroll
        for (int kk = 0; kk < 32; ++kk)
            fma16g(xf[kk], W1 + (c * 32 + kk) * 16, acc);
    }
    float dv = dinv[row];
    union { __half2 h[8]; uint4 u[2]; } pk;
    #pragma unroll
    for (int o = 0; o < 8; ++o)
        pk.h[o] = __floats2half2_rn(acc[2 * o] * dv, acc[2 * o + 1] * dv);
    uint4* dst = (uint4*)(h1h + (size_t)row * 8);
    dst[0] = pk.u[0];
    dst[1] = pk.u[1];
}

// ---------- K8: fused gather-1 + gemm2 — node per 8-lane group ----------
// One coalesced ecol load per lane; indices shuffle-distributed within the group.
__global__ __launch_bounds__(256) void k_gathm(const unsigned* __restrict__ cursor,
                                               const int* __restrict__ ecol,
                                               const float* __restrict__ dinv,
                                               const float* __restrict__ b1,
                                               const float* __restrict__ W2,
                                               const __half2* __restrict__ h1h,
                                               __half2* __restrict__ h2h) {
    __shared__ float Ws[512];   // W2 [16][32]
    __shared__ float B1[16];
    int tid = threadIdx.x;
    Ws[tid] = W2[tid];
    Ws[tid + 256] = W2[tid + 256];
    if (tid < 16) B1[tid] = b1[tid];
    __syncthreads();
    int lane = tid & 63;
    int grp = lane >> 3, f2 = lane & 7;
    int gb = lane & 56;
    int node = blockIdx.x * 32 + (tid >> 6) * 8 + grp;
    unsigned s = node ? cursor[node - 1] : 0u;
    unsigned e = cursor[node];
    float2 acc = __half22float2(h1h[(size_t)node * 8 + f2]);   // self term
    for (unsigned j = s; j < e; j += 8) {
        unsigned jj = j + (unsigned)f2;
        int myc = ecol[jj < e ? jj : j];
        int cq[8];
        #pragma unroll
        for (int q = 0; q < 8; ++q) cq[q] = __shfl(myc, gb + q);
        float2 a[8];
        #pragma unroll
        for (int q = 0; q < 8; ++q)
            a[q] = __half22float2(h1h[(size_t)cq[q] * 8 + f2]);
        #pragma unroll
        for (int q = 0; q < 8; ++q) {
            float m = (j + q < e) ? 1.f : 0.f;
            acc.x += m * a[q].x;
            acc.y += m * a[q].y;
        }
    }
    float dv = dinv[node];
    float r0 = fmaxf(acc.x * dv + B1[2 * f2], 0.f);
    float r1 = fmaxf(acc.y * dv + B1[2 * f2 + 1], 0.f);
    float rv[16];
    #pragma unroll
    for (int q = 0; q < 8; ++q) {
        rv[2 * q]     = __shfl(r0, gb + q);
        rv[2 * q + 1] = __shfl(r1, gb + q);
    }
    float o0x = 0.f, o0y = 0.f, o1x = 0.f, o1y = 0.f;
    #pragma unroll
    for (int q = 0; q < 16; ++q) {
        float r = rv[q];
        o0x += r * Ws[q * 32 + 2 * f2];
        o0y += r * Ws[q * 32 + 2 * f2 + 1];
        o1x += r * Ws[q * 32 + 2 * f2 + 16];
        o1y += r * Ws[q * 32 + 2 * f2 + 17];
    }
    h2h[(size_t)node * 16 + f2]     = __floats2half2_rn(o0x * dv, o0y * dv);
    h2h[(size_t)node * 16 + f2 + 8] = __floats2half2_rn(o1x * dv, o1y * dv);
}

// ---------- K9: gather layer 2 — node per 16-lane group, 16 edges in flight ----------
__global__ __launch_bounds__(256) void k_gath2(const unsigned* __restrict__ cursor,
                                               const int* __restrict__ ecol,
                                               const float* __restrict__ dinv,
                                               const float* __restrict__ b2,
                                               const __half2* __restrict__ h2h,
                                               __half2* __restrict__ out2h) {
    int tid = threadIdx.x;
    int lane = tid & 63;
    int grp = lane >> 4, f2 = lane & 15;
    int gb = lane & 48;
    int node = blockIdx.x * 16 + (tid >> 6) * 4 + grp;
    unsigned s = node ? cursor[node - 1] : 0u;
    unsigned e = cursor[node];
    float2 acc = __half22float2(h2h[(size_t)node * 16 + f2]);  // self term
    for (unsigned j = s; j < e; j += 16) {
        unsigned jj = j + (unsigned)f2;
        int myc = ecol[jj < e ? jj : j];
        int cq[16];
        #pragma unroll
        for (int q = 0; q < 16; ++q) cq[q] = __shfl(myc, gb + q);
        float2 a[16];
        #pragma unroll
        for (int q = 0; q < 16; ++q)
            a[q] = __half22float2(h2h[(size_t)cq[q] * 16 + f2]);
        #pragma unroll
        for (int q = 0; q < 16; ++q) {
            float m = (j + q < e) ? 1.f : 0.f;
            acc.x += m * a[q].x;
            acc.y += m * a[q].y;
        }
    }
    float dv = dinv[node];
    float2 b = ((const float2*)b2)[f2];
    out2h[(size_t)node * 16 + f2] =
        __floats2half2_rn(acc.x * dv + b.x, acc.y * dv + b.y);
}

// ---------- K10: conv1d(32->64, k=3, pad 1) + global max (fp16 input) ----------
#define NPB 256
__global__ __launch_bounds__(256) void k_conv(const __half2* __restrict__ h2f,
                                              const float* __restrict__ cw,
                                              unsigned* __restrict__ pool) {
    __shared__ float Hs[NPB + 2][33];
    __shared__ float Wt[3 * 32 * 64];
    __shared__ float4 Ms[4][16];
    int tid = threadIdx.x;
    int base = blockIdx.x * NPB;
    for (int idx = tid; idx < 6144; idx += 256) {
        int o = idx / 96, r = idx % 96, ci = r / 3, k = r % 3;
        Wt[(k * 32 + ci) * 64 + o] = cw[idx];
    }
    // stage rows base-1 .. base+256 from fp16: 4 x uint4 per row (uint4 = 4 half2)
    for (int idx = tid; idx < (NPB + 2) * 4; idx += 256) {
        int j = idx >> 2, qt = idx & 3;
        int g = base + j - 1;
        if (g >= 0 && g < NN) {
            uint4 v = *(const uint4*)(h2f + (size_t)g * 16 + qt * 4);
            const __half2* hp = (const __half2*)&v;
            #pragma unroll
            for (int q = 0; q < 4; ++q) {
                float2 f = __half22float2(hp[q]);
                Hs[j][qt * 8 + 2 * q]     = f.x;
                Hs[j][qt * 8 + 2 * q + 1] = f.y;
            }
        } else {
            #pragma unroll
            for (int q = 0; q < 8; ++q) Hs[j][qt * 8 + q] = 0.f;
        }
    }
    __syncthreads();

    int o4 = (tid & 15) * 4;
    int ng = tid >> 4;
    float4 acc[16] = {};
    for (int ci = 0; ci < 32; ++ci) {
        float h[18];
        #pragma unroll
        for (int j = 0; j < 18; ++j) h[j] = Hs[ng * 16 + j][ci];
        #pragma unroll
        for (int k = 0; k < 3; ++k) {
            float4 w = *(const float4*)&Wt[(k * 32 + ci) * 64 + o4];
            #pragma unroll
            for (int i = 0; i < 16; ++i) {
                float hv = h[i + k];
                acc[i].x += hv * w.x;
                acc[i].y += hv * w.y;
                acc[i].z += hv * w.z;
                acc[i].w += hv * w.w;
            }
        }
    }
    const float NI = -3.0e38f;
    float4 m4 = make_float4(NI, NI, NI, NI);
    #pragma unroll
    for (int i = 0; i < 16; ++i) {
        if (base + ng * 16 + i < NN) {
            m4.x = fmaxf(m4.x, acc[i].x);
            m4.y = fmaxf(m4.y, acc[i].y);
            m4.z = fmaxf(m4.z, acc[i].z);
            m4.w = fmaxf(m4.w, acc[i].w);
        }
    }
    #pragma unroll
    for (int off = 16; off <= 32; off <<= 1) {
        m4.x = fmaxf(m4.x, __shfl_xor(m4.x, off));
        m4.y = fmaxf(m4.y, __shfl_xor(m4.y, off));
        m4.z = fmaxf(m4.z, __shfl_xor(m4.z, off));
        m4.w = fmaxf(m4.w, __shfl_xor(m4.w, off));
    }
    int lane = tid & 63, wv = tid >> 6;
    if (lane < 16) Ms[wv][lane] = m4;
    __syncthreads();
    if (tid < 16) {
        float4 a = Ms[0][tid], b = Ms[1][tid], c = Ms[2][tid], d = Ms[3][tid];
        a.x = fmaxf(fmaxf(a.x, b.x), fmaxf(c.x, d.x));
        a.y = fmaxf(fmaxf(a.y, b.y), fmaxf(c.y, d.y));
        a.z = fmaxf(fmaxf(a.z, b.z), fmaxf(c.z, d.z));
        a.w = fmaxf(fmaxf(a.w, b.w), fmaxf(c.w, d.w));
        int o = tid * 4;
        atomicMax(&pool[o + 0], enc_f(a.x));
        atomicMax(&pool[o + 1], enc_f(a.y));
        atomicMax(&pool[o + 2], enc_f(a.z));
        atomicMax(&pool[o + 3], enc_f(a.w));
    }
}

// ---------- K11: out = (pooled + conv_b) @ fc_w^T + fc_b ----------
__global__ void k_fc(const unsigned* __restrict__ pool, const float* __restrict__ cb,
                     const float* __restrict__ fw, const float* __restrict__ fb,
                     float* __restrict__ out) {
    __shared__ float P[64];
    int tid = threadIdx.x;
    if (tid < 64) P[tid] = dec_f(pool[tid]) + cb[tid];
    __syncthreads();
    int j = blockIdx.x * 256 + tid;
    if (j >= NC) return;
    float s = fb[j];
    const float4* wr = (const float4*)(fw + (size_t)j * CO);
    #pragma unroll
    for (int c = 0; c < 16; ++c) {
        float4 w = wr[c];
        s += P[c * 4 + 0] * w.x + P[c * 4 + 1] * w.y +
             P[c * 4 + 2] * w.z + P[c * 4 + 3] * w.w;
    }
    out[j] = s;
}

extern "C" void kernel_launch(void* const* d_in, const int* in_sizes, int n_in,
                              void* d_out, int out_size, void* d_ws, size_t ws_size,
                              hipStream_t stream) {
    const float* x  = (const float*)d_in[0];
    const int*   ei = (const int*)d_in[1];
    const float* W1 = (const float*)d_in[2];
    const float* b1 = (const float*)d_in[3];
    const float* W2 = (const float*)d_in[4];
    const float* b2 = (const float*)d_in[5];
    const float* cw = (const float*)d_in[6];
    const float* cb = (const float*)d_in[7];
    const float* fw = (const float*)d_in[8];
    const float* fb = (const float*)d_in[9];

    float* ws = (float*)d_ws;
    float*    dinv   = ws + OFF_DINV;
    unsigned* cursor = (unsigned*)(ws + OFF_CUR);
    unsigned* deg    = (unsigned*)(ws + OFF_DEG);
    int*      ecol   = (int*)(ws + OFF_ECOL);
    unsigned* pcur   = (unsigned*)(ws + OFF_MISC);
    unsigned* pool   = pcur + 256;
    unsigned* bsum   = pcur + 320;
    unsigned* epart  = (unsigned*)(ws + OFF_EPART);
    unsigned* hist   = (unsigned*)(ws + OFF_HIST);
    __half2*  h1h    = (__half2*)(ws + OFF_H1S);
    __half2*  h2h    = (__half2*)(ws + OFF_H2S);
    __half2*  out2h  = (__half2*)(ws + OFF_OUT2H);

    k_init   <<<1, 256, 0, stream>>>(pcur, pool);
    k_bucket <<<NE / (256 * BK), 256, 0, stream>>>(ei, pcur, epart);        // 625
    k_hist   <<<NPART * NGRP, 256, 0, stream>>>(pcur, epart, hist);         // 256
    k_colscan<<<NBLK, 256, 0, stream>>>(hist, deg, bsum);
    k_bscan  <<<1, 512, 0, stream>>>(bsum);
    k_cscan  <<<NBLK, 256, 0, stream>>>(deg, bsum, cursor, dinv);
    k_place  <<<NPART * NGRP, 256, 0, stream>>>(pcur, epart, hist, cursor, ecol);
    k_gemm1  <<<GBLK, 64, 0, stream>>>(x, W1, dinv, h1h);                   // 1563
    k_gathm  <<<NN / 32, 256, 0, stream>>>(cursor, ecol, dinv, b1, W2, h1h, h2h);   // 3125
    k_gath2  <<<NN / 16, 256, 0, stream>>>(cursor, ecol, dinv, b2, h2h, out2h);     // 6250
    k_conv   <<<(NN + NPB - 1) / NPB, 256, 0, stream>>>(out2h, cw, pool);
    k_fc     <<<4, 256, 0, stream>>>(pool, cb, fw, fb, (float*)d_out);
}